// Round 1
// baseline (4157.552 us; speedup 1.0000x reference)
//
#include <hip/hip_runtime.h>

#define HEADS 8
#define HD 64
#define NB 8
#define SEQ 1024
#define EMB 512
#define FFD 2048
#define NROWS (NB*SEQ)   // 8192
#define LNEPS 1e-5f

// ---------------- block reductions (256 threads = 4 waves) ----------------
__device__ __forceinline__ float block_sum(float v){
  #pragma unroll
  for(int k=32;k>=1;k>>=1) v += __shfl_xor(v,k,64);
  __shared__ float s[4];
  int w = threadIdx.x>>6;
  __syncthreads();
  if((threadIdx.x&63)==0) s[w]=v;
  __syncthreads();
  return s[0]+s[1]+s[2]+s[3];
}
__device__ __forceinline__ float block_max(float v){
  #pragma unroll
  for(int k=32;k>=1;k>>=1) v = fmaxf(v,__shfl_xor(v,k,64));
  __shared__ float s[4];
  int w = threadIdx.x>>6;
  __syncthreads();
  if((threadIdx.x&63)==0) s[w]=v;
  __syncthreads();
  return fmaxf(fmaxf(s[0],s[1]),fmaxf(s[2],s[3]));
}
__device__ __forceinline__ float2 block_sum2(float a,float b){
  #pragma unroll
  for(int k=32;k>=1;k>>=1){ a += __shfl_xor(a,k,64); b += __shfl_xor(b,k,64); }
  __shared__ float sa[4], sb[4];
  int w = threadIdx.x>>6;
  __syncthreads();
  if((threadIdx.x&63)==0){ sa[w]=a; sb[w]=b; }
  __syncthreads();
  return make_float2(sa[0]+sa[1]+sa[2]+sa[3], sb[0]+sb[1]+sb[2]+sb[3]);
}

// ---------------- generic fp32 GEMM: C = A * op(B) + bias ----------------
// A: [M,K] lda. TRANSB: B [N,K] ldb (C=A*B^T); else B [K,N] ldb.
// M = gridDim.y*64, N = gridDim.x*64. K multiple of 16; M,N multiples of 64.
template<bool TRANSB,bool RELU,bool BIAS>
__global__ __launch_bounds__(256) void gemm_f32(
    const float* __restrict__ Ag, const float* __restrict__ Bg,
    const float* __restrict__ biasg, float* __restrict__ Cg,
    int K, int lda, int ldb, int ldc,
    long long strA, long long strB, long long strC)
{
  const float* Ab = Ag + blockIdx.z*strA;
  const float* Bb = Bg + blockIdx.z*strB;
  float* Cb = Cg + blockIdx.z*strC;
  const int m0 = blockIdx.y*64, n0 = blockIdx.x*64;
  __shared__ float As[16][68];
  __shared__ float Bs[16][68];
  const int t = threadIdx.x;
  const int tm = t & 15, tn = t >> 4;
  float acc[4][4] = {};
  for(int k0=0;k0<K;k0+=16){
    {
      int r = t>>2, c = (t&3)*4;
      float4 v = *(const float4*)(Ab + (long long)(m0+r)*lda + k0 + c);
      As[c][r]=v.x; As[c+1][r]=v.y; As[c+2][r]=v.z; As[c+3][r]=v.w;
    }
    if(TRANSB){
      int r = t>>2, c = (t&3)*4;
      float4 v = *(const float4*)(Bb + (long long)(n0+r)*ldb + k0 + c);
      Bs[c][r]=v.x; Bs[c+1][r]=v.y; Bs[c+2][r]=v.z; Bs[c+3][r]=v.w;
    } else {
      int r = t>>4, c = (t&15)*4;
      float4 v = *(const float4*)(Bb + (long long)(k0+r)*ldb + n0 + c);
      Bs[r][c]=v.x; Bs[r][c+1]=v.y; Bs[r][c+2]=v.z; Bs[r][c+3]=v.w;
    }
    __syncthreads();
    #pragma unroll
    for(int kk=0;kk<16;kk++){
      float a[4], bb[4];
      #pragma unroll
      for(int i=0;i<4;i++) a[i] = As[kk][tm*4+i];
      #pragma unroll
      for(int j=0;j<4;j++) bb[j] = Bs[kk][tn*4+j];
      #pragma unroll
      for(int i=0;i<4;i++)
        #pragma unroll
        for(int j=0;j<4;j++)
          acc[i][j] = fmaf(a[i], bb[j], acc[i][j]);
    }
    __syncthreads();
  }
  #pragma unroll
  for(int i=0;i<4;i++){
    float* orow = Cb + (long long)(m0+tm*4+i)*ldc + n0 + tn*4;
    float4 o;
    #pragma unroll
    for(int j=0;j<4;j++){
      float v = acc[i][j];
      if(BIAS) v += biasg[n0+tn*4+j];
      if(RELU) v = fmaxf(v, 0.f);
      (&o.x)[j] = v;
    }
    *(float4*)orow = o;
  }
}

// ------- per-head row softmax (with 1/8 logit scale) -> mean-accumulate -------
// logits: [8192,1024] raw q.k for one head; A accumulates mean_h softmax.
template<bool INIT>
__global__ __launch_bounds__(256) void softmax_mean_acc(
    const float* __restrict__ logits, float* __restrict__ A)
{
  const long long row = blockIdx.x;
  const float* lrow = logits + row*1024;
  float* arow = A + row*1024;
  const int t = threadIdx.x;
  float4 lv = ((const float4*)lrow)[t];
  float m = block_max(fmaxf(fmaxf(lv.x,lv.y),fmaxf(lv.z,lv.w)));
  float e0 = __expf((lv.x-m)*0.125f);
  float e1 = __expf((lv.y-m)*0.125f);
  float e2 = __expf((lv.z-m)*0.125f);
  float e3 = __expf((lv.w-m)*0.125f);
  float s = block_sum(e0+e1+e2+e3);
  float inv = 0.125f / s;   // 1/8 head-mean folded in
  float4 o;
  if(INIT){
    o.x = e0*inv; o.y = e1*inv; o.z = e2*inv; o.w = e3*inv;
  } else {
    float4 p = ((const float4*)arow)[t];
    o.x = p.x + e0*inv; o.y = p.y + e1*inv; o.z = p.z + e2*inv; o.w = p.w + e3*inv;
  }
  ((float4*)arow)[t] = o;
}

// ------- causal mask + additive position bias + second softmax, in place -------
__global__ __launch_bounds__(256) void causal_pos_softmax(float* __restrict__ A)
{
  const long long row = blockIdx.x;
  const int i = (int)(row & (SEQ-1));
  float* arow = A + row*1024;
  const int t = threadIdx.x;
  float4 av = ((const float4*)arow)[t];
  float v[4];
  #pragma unroll
  for(int q=0;q<4;q++){
    int j = t*4+q;
    float a = (&av.x)[q];
    v[q] = (j<=i) ? (a + __expf((float)(j-i)*0.1f)) : -1e30f;
  }
  float m = block_max(fmaxf(fmaxf(v[0],v[1]),fmaxf(v[2],v[3])));
  float e[4]; float ls = 0.f;
  #pragma unroll
  for(int q=0;q<4;q++){
    e[q] = (t*4+q <= i) ? __expf(v[q]-m) : 0.f;
    ls += e[q];
  }
  float s = block_sum(ls);
  float inv = 1.f/s;
  float4 o = { e[0]*inv, e[1]*inv, e[2]*inv, e[3]*inv };
  ((float4*)arow)[t] = o;
}

// ------- fused residual + LN1 + LN2 (row = 512) -------
__global__ __launch_bounds__(256) void residual_ln2(
    const float* __restrict__ X, const float* __restrict__ R,
    const float* __restrict__ g1, const float* __restrict__ b1,
    const float* __restrict__ g2, const float* __restrict__ b2,
    float* __restrict__ O)
{
  const long long row = blockIdx.x;
  const int t = threadIdx.x;
  const float* xr = X + row*EMB;
  const float* rr = R + row*EMB;
  float v0 = xr[t]     + rr[t];
  float v1 = xr[t+256] + rr[t+256];
  float2 ss = block_sum2(v0+v1, v0*v0+v1*v1);
  float mean = ss.x*(1.f/EMB);
  float var  = ss.y*(1.f/EMB) - mean*mean;
  float rstd = rsqrtf(var + LNEPS);
  float y0 = (v0-mean)*rstd*g1[t]     + b1[t];
  float y1 = (v1-mean)*rstd*g1[t+256] + b1[t+256];
  ss = block_sum2(y0+y1, y0*y0+y1*y1);
  mean = ss.x*(1.f/EMB);
  var  = ss.y*(1.f/EMB) - mean*mean;
  rstd = rsqrtf(var + LNEPS);
  float* orow = O + row*EMB;
  orow[t]     = (y0-mean)*rstd*g2[t]     + b2[t];
  orow[t+256] = (y1-mean)*rstd*g2[t+256] + b2[t+256];
}

// ------- residual + LN (row = 512) -------
__global__ __launch_bounds__(256) void residual_ln(
    const float* __restrict__ X, const float* __restrict__ R,
    const float* __restrict__ g, const float* __restrict__ b,
    float* __restrict__ O)
{
  const long long row = blockIdx.x;
  const int t = threadIdx.x;
  const float* xr = X + row*EMB;
  const float* rr = R + row*EMB;
  float v0 = xr[t]     + rr[t];
  float v1 = xr[t+256] + rr[t+256];
  float2 ss = block_sum2(v0+v1, v0*v0+v1*v1);
  float mean = ss.x*(1.f/EMB);
  float var  = ss.y*(1.f/EMB) - mean*mean;
  float rstd = rsqrtf(var + LNEPS);
  float* orow = O + row*EMB;
  orow[t]     = (v0-mean)*rstd*g[t]     + b[t];
  orow[t+256] = (v1-mean)*rstd*g[t+256] + b[t+256];
}

extern "C" void kernel_launch(void* const* d_in, const int* in_sizes, int n_in,
                              void* d_out, int out_size, void* d_ws, size_t ws_size,
                              hipStream_t stream)
{
  const float* x_in = (const float*)d_in[0];
  const float* Wqkv = (const float*)d_in[1];
  const float* bqkv = (const float*)d_in[2];
  const float* W1   = (const float*)d_in[3];
  const float* b1   = (const float*)d_in[4];
  const float* W2   = (const float*)d_in[5];
  const float* b2   = (const float*)d_in[6];
  const float* g1   = (const float*)d_in[7];
  const float* bt1  = (const float*)d_in[8];
  const float* g2   = (const float*)d_in[9];
  const float* bt2  = (const float*)d_in[10];
  const float* g3   = (const float*)d_in[11];
  const float* bt3  = (const float*)d_in[12];

  float* X = (float*)d_out;                              // running activations [8192,512]

  char* ws = (char*)d_ws;
  float* buf0 = (float*)(ws);                            // 64MB: qkv [8192,1536] then h [8192,2048]
  float* Amat = (float*)(ws + ((size_t)64<<20));         // 32MB: A / W [8,1024,1024]
  float* tmp  = (float*)(ws + ((size_t)96<<20));         // 16MB: sa / ff [8192,512]
  float* lbuf = (float*)(ws + ((size_t)112<<20));        // 32MB: per-head logits [8192,1024]

  hipMemcpyAsync(X, x_in, (size_t)NROWS*EMB*sizeof(float),
                 hipMemcpyDeviceToDevice, stream);

  for(int d=0; d<4; d++){
    const float* Wq = Wqkv + (size_t)d*3*EMB*EMB;
    const float* bq = bqkv + (size_t)d*3*EMB;

    // qkv = X * Wq^T + bq   -> buf0 [8192,1536]
    gemm_f32<true,false,true><<<dim3(1536/64, NROWS/64, 1),256,0,stream>>>(
        X, Wq, bq, buf0, EMB, EMB, EMB, 3*EMB, 0,0,0);

    // per-head: logits = q*k^T (raw), then row-softmax(x/8) mean-accumulated into Amat
    for(int h=0; h<HEADS; h++){
      gemm_f32<true,false,false><<<dim3(SEQ/64, SEQ/64, NB),256,0,stream>>>(
          buf0 + h*HD, buf0 + EMB + h*HD, nullptr, lbuf,
          HD, 3*EMB, 3*EMB, SEQ,
          (long long)SEQ*3*EMB, (long long)SEQ*3*EMB, (long long)SEQ*SEQ);
      if(h==0) softmax_mean_acc<true ><<<NROWS,256,0,stream>>>(lbuf, Amat);
      else     softmax_mean_acc<false><<<NROWS,256,0,stream>>>(lbuf, Amat);
    }

    // W = softmax(causal(A) + pos) in place
    causal_pos_softmax<<<NROWS,256,0,stream>>>(Amat);

    // sa = W @ X (values are raw layer input)  -> tmp
    gemm_f32<false,false,false><<<dim3(EMB/64, SEQ/64, NB),256,0,stream>>>(
        Amat, X, nullptr, tmp, SEQ, SEQ, EMB, EMB,
        (long long)SEQ*SEQ, (long long)SEQ*EMB, (long long)SEQ*EMB);

    // x = LN2(LN1(x + sa))
    residual_ln2<<<NROWS,256,0,stream>>>(X, tmp, g1+d*EMB, bt1+d*EMB,
                                         g2+d*EMB, bt2+d*EMB, X);

    // h = relu(X*W1^T + b1) -> buf0 [8192,2048]
    gemm_f32<true,true,true><<<dim3(FFD/64, NROWS/64, 1),256,0,stream>>>(
        X, W1 + (size_t)d*FFD*EMB, b1 + (size_t)d*FFD, buf0,
        EMB, EMB, EMB, FFD, 0,0,0);

    // ff = h*W2^T + b2 -> tmp
    gemm_f32<true,false,true><<<dim3(EMB/64, NROWS/64, 1),256,0,stream>>>(
        buf0, W2 + (size_t)d*EMB*FFD, b2 + (size_t)d*EMB, tmp,
        FFD, FFD, FFD, EMB, 0,0,0);

    // x = LN3(x + ff)
    residual_ln<<<NROWS,256,0,stream>>>(X, tmp, g3+d*EMB, bt3+d*EMB, X);
  }
}

// Round 2
// 1427.673 us; speedup vs baseline: 2.9121x; 2.9121x over previous
//
#include <hip/hip_runtime.h>

#define NB 8
#define SEQ 1024
#define EMB 512
#define FFD 2048
#define NROWS (NB*SEQ)   // 8192
#define LNEPS 1e-5f
#define KP 520           // LDS row pitch for staged K tiles (512 + 8 pad)

typedef __bf16 bf16x8 __attribute__((ext_vector_type(8)));
typedef float f32x4 __attribute__((ext_vector_type(4)));

__device__ __forceinline__ unsigned short f2bf(float f){
  unsigned u = __builtin_bit_cast(unsigned, f);
  u += 0x7fffu + ((u>>16)&1u);
  return (unsigned short)(u>>16);
}
__device__ __forceinline__ bf16x8 ld_bf8(const unsigned short* p){
  return *(const bf16x8*)p;
}
__device__ __forceinline__ void async_copy16(const void* g, void* l){
  __builtin_amdgcn_global_load_lds((const __attribute__((address_space(1))) unsigned int*)g,
                                   (__attribute__((address_space(3))) unsigned int*)l,
                                   16, 0, 0);
}

// ---------------- block reductions (256 threads = 4 waves) ----------------
__device__ __forceinline__ float2 block_sum2(float a,float b){
  #pragma unroll
  for(int k=32;k>=1;k>>=1){ a += __shfl_xor(a,k,64); b += __shfl_xor(b,k,64); }
  __shared__ float sa[4], sb[4];
  int w = threadIdx.x>>6;
  __syncthreads();
  if((threadIdx.x&63)==0){ sa[w]=a; sb[w]=b; }
  __syncthreads();
  return make_float2(sa[0]+sa[1]+sa[2]+sa[3], sb[0]+sb[1]+sb[2]+sb[3]);
}

// ---------------- bf16 MFMA GEMM: C = A * B^T (+bias) ----------------
// A [M,K] bf16 lda; B [N,K] bf16 ldb. 128x128 tile, BK=32, 4 waves (2x2 of 64x64).
// CAUSAL: k-loop limited to m0+128 (A rows are query index, k is key index).
template<bool OUTBF16, bool RELU, bool BIAS, bool CAUSAL>
__global__ __launch_bounds__(256) void gemm_bf16(
    const unsigned short* __restrict__ Ag, const unsigned short* __restrict__ Bg,
    const float* __restrict__ bias, void* __restrict__ Cg,
    int K, int lda, int ldb, int ldc,
    long long strA, long long strB, long long strC)
{
  __shared__ unsigned short As[128*32];
  __shared__ unsigned short Bs[128*32];
  const unsigned short* Ab = Ag + blockIdx.z*strA;
  const unsigned short* Bb = Bg + blockIdx.z*strB;
  const int m0 = blockIdx.y*128, n0 = blockIdx.x*128;
  const int t = threadIdx.x;
  const int lane = t & 63, w = t >> 6;
  const int wy = w >> 1, wx = w & 1;
  const int q = lane >> 4, c = lane & 15;
  f32x4 acc[4][4] = {};
  const int kend = CAUSAL ? (m0 + 128) : K;
  const int srow = t >> 2, skoff = (t & 3) * 8;   // lds offset = 16*t (lane-contiguous)
  for(int k0 = 0; k0 < kend; k0 += 32){
    async_copy16(Ab + (long long)(m0 + srow)*lda + k0 + skoff,      As + srow*32 + skoff);
    async_copy16(Ab + (long long)(m0 + srow + 64)*lda + k0 + skoff, As + (srow+64)*32 + skoff);
    async_copy16(Bb + (long long)(n0 + srow)*ldb + k0 + skoff,      Bs + srow*32 + skoff);
    async_copy16(Bb + (long long)(n0 + srow + 64)*ldb + k0 + skoff, Bs + (srow+64)*32 + skoff);
    __syncthreads();
    bf16x8 af[4], bfr[4];
    #pragma unroll
    for(int fi=0; fi<4; fi++) af[fi]  = ld_bf8(As + (wy*64 + fi*16 + c)*32 + q*8);
    #pragma unroll
    for(int fj=0; fj<4; fj++) bfr[fj] = ld_bf8(Bs + (wx*64 + fj*16 + c)*32 + q*8);
    #pragma unroll
    for(int fi=0; fi<4; fi++)
      #pragma unroll
      for(int fj=0; fj<4; fj++)
        acc[fi][fj] = __builtin_amdgcn_mfma_f32_16x16x32_bf16(af[fi], bfr[fj], acc[fi][fj], 0,0,0);
    __syncthreads();
  }
  #pragma unroll
  for(int fi=0; fi<4; fi++){
    #pragma unroll
    for(int fj=0; fj<4; fj++){
      const int row = m0 + wy*64 + fi*16 + q*4;
      const int col = n0 + wx*64 + fj*16 + c;
      const float bv = BIAS ? bias[col] : 0.f;
      #pragma unroll
      for(int r=0; r<4; r++){
        float v = acc[fi][fj][r] + bv;
        if(RELU) v = fmaxf(v, 0.f);
        long long off = blockIdx.z*strC + (long long)(row+r)*ldc + col;
        if(OUTBF16) ((unsigned short*)Cg)[off] = f2bf(v);
        else        ((float*)Cg)[off] = v;
      }
    }
  }
}

// ---------------- attention pass 1: per-head softmax denominators ----------------
// invd8[b][h][i] = 1/(8 * sum_j exp(q_i.k_j / 8)).  Grid (SEQ/32, NB), 256 thr.
// Waves: (jh = w>>1) splits j-chunks, (rh = w&1) splits 32 rows into 2x16.
__global__ __launch_bounds__(256) void attn_pass1(
    const unsigned short* __restrict__ qkv, float* __restrict__ invd8)
{
  __shared__ unsigned short Ks[2][16*KP];
  __shared__ float DA[2][8][32];
  const int b = blockIdx.y;
  const int i0 = blockIdx.x * 32;
  const int t = threadIdx.x, lane = t & 63, w = t >> 6;
  const int jh = w >> 1, rh = w & 1;
  const int q = lane >> 4, c = lane & 15;
  const int irow = i0 + rh*16 + c;
  bf16x8 qf[8][2];
  #pragma unroll
  for(int h=0; h<8; h++){
    const unsigned short* qp = qkv + ((long long)(b*SEQ + irow))*1024 + h*64 + q*8;
    qf[h][0] = ld_bf8(qp);
    qf[h][1] = ld_bf8(qp + 32);
  }
  float dacc[8][4] = {};
  for(int it=0; it<32; ++it){
    __syncthreads();
    #pragma unroll
    for(int u=0; u<8; u++){
      int f = t*8 + u;               // 2048 chunks of 16B
      int buf = f >> 10, ff = f & 1023;
      int row = ff >> 6, cc = (ff & 63) * 8;
      int j0 = (2*it + buf) * 16;
      uint4 v = *(const uint4*)(qkv + ((long long)(b*SEQ + j0 + row))*1024 + 512 + cc);
      *(uint4*)(&Ks[buf][row*KP + cc]) = v;
    }
    __syncthreads();
    #pragma unroll
    for(int h=0; h<8; h++){
      bf16x8 k0v = ld_bf8(&Ks[jh][c*KP + h*64 + q*8]);
      bf16x8 k1v = ld_bf8(&Ks[jh][c*KP + h*64 + 32 + q*8]);
      f32x4 l = {0.f,0.f,0.f,0.f};
      l = __builtin_amdgcn_mfma_f32_16x16x32_bf16(qf[h][0], k0v, l, 0,0,0);
      l = __builtin_amdgcn_mfma_f32_16x16x32_bf16(qf[h][1], k1v, l, 0,0,0);
      #pragma unroll
      for(int r=0; r<4; r++) dacc[h][r] += __expf(l[r]*0.125f);
    }
  }
  #pragma unroll
  for(int h=0; h<8; h++)
    #pragma unroll
    for(int r=0; r<4; r++){
      #pragma unroll
      for(int m=1; m<16; m<<=1) dacc[h][r] += __shfl_xor(dacc[h][r], m, 16);
    }
  if(c == 0){
    #pragma unroll
    for(int h=0; h<8; h++)
      #pragma unroll
      for(int r=0; r<4; r++) DA[jh][h][rh*16 + q*4 + r] = dacc[h][r];
  }
  __syncthreads();
  { int h = t >> 5, rr = t & 31;
    invd8[((long long)(b*8 + h))*SEQ + i0 + rr] = 1.f/(8.f*(DA[0][h][rr] + DA[1][h][rr])); }
}

// ---------------- attention pass 2: averaged A + pos/causal + 2nd softmax ----------------
// Writes unnormalized w (bf16) into Wm[b][i][j] and invD[b*SEQ+i] = 1/sum_j w.
__global__ __launch_bounds__(256) void attn_pass2(
    const unsigned short* __restrict__ qkv, const float* __restrict__ invd8,
    unsigned short* __restrict__ Wm, float* __restrict__ invD)
{
  __shared__ unsigned short Ks[2][16*KP];
  __shared__ float DD[2][32];
  const int b = blockIdx.y;
  const int i0 = blockIdx.x * 32;
  const int t = threadIdx.x, lane = t & 63, w = t >> 6;
  const int jh = w >> 1, rh = w & 1;
  const int q = lane >> 4, c = lane & 15;
  const int irow = i0 + rh*16 + c;
  bf16x8 qf[8][2];
  #pragma unroll
  for(int h=0; h<8; h++){
    const unsigned short* qp = qkv + ((long long)(b*SEQ + irow))*1024 + h*64 + q*8;
    qf[h][0] = ld_bf8(qp);
    qf[h][1] = ld_bf8(qp + 32);
  }
  float id8[8][4];
  #pragma unroll
  for(int h=0; h<8; h++)
    #pragma unroll
    for(int r=0; r<4; r++)
      id8[h][r] = invd8[((long long)(b*8 + h))*SEQ + i0 + rh*16 + q*4 + r];
  float Dacc[4] = {};
  const int T = i0/32 + 1;
  for(int it=0; it<T; ++it){
    __syncthreads();
    #pragma unroll
    for(int u=0; u<8; u++){
      int f = t*8 + u;
      int buf = f >> 10, ff = f & 1023;
      int row = ff >> 6, cc = (ff & 63) * 8;
      int j0 = (2*it + buf) * 16;
      uint4 v = *(const uint4*)(qkv + ((long long)(b*SEQ + j0 + row))*1024 + 512 + cc);
      *(uint4*)(&Ks[buf][row*KP + cc]) = v;
    }
    __syncthreads();
    const int j0 = (2*it + jh) * 16;
    if(j0 <= i0 + rh*16 + 15){
      float at[4] = {};
      #pragma unroll
      for(int h=0; h<8; h++){
        bf16x8 k0v = ld_bf8(&Ks[jh][c*KP + h*64 + q*8]);
        bf16x8 k1v = ld_bf8(&Ks[jh][c*KP + h*64 + 32 + q*8]);
        f32x4 l = {0.f,0.f,0.f,0.f};
        l = __builtin_amdgcn_mfma_f32_16x16x32_bf16(qf[h][0], k0v, l, 0,0,0);
        l = __builtin_amdgcn_mfma_f32_16x16x32_bf16(qf[h][1], k1v, l, 0,0,0);
        #pragma unroll
        for(int r=0; r<4; r++) at[r] += __expf(l[r]*0.125f) * id8[h][r];
      }
      const int j = j0 + c;
      #pragma unroll
      for(int r=0; r<4; r++){
        const int i = i0 + rh*16 + q*4 + r;
        if(j <= i){
          float wv = __expf(at[r] + __expf((float)(j - i)*0.1f));
          Dacc[r] += wv;
          Wm[((long long)(b*SEQ + i))*SEQ + j] = f2bf(wv);
        }
      }
    }
  }
  #pragma unroll
  for(int r=0; r<4; r++){
    #pragma unroll
    for(int m=1; m<16; m<<=1) Dacc[r] += __shfl_xor(Dacc[r], m, 16);
  }
  if(c == 0){
    #pragma unroll
    for(int r=0; r<4; r++) DD[jh][rh*16 + q*4 + r] = Dacc[r];
  }
  __syncthreads();
  if(t < 32) invD[b*SEQ + i0 + t] = 1.f/(DD[0][t] + DD[1][t]);
}

// ------- fused residual(+invD scale) + LN1 + LN2; writes fp32 + bf16 -------
__global__ __launch_bounds__(256) void residual_ln2(
    const float* __restrict__ X, const float* __restrict__ SA,
    const float* __restrict__ invD,
    const float* __restrict__ g1, const float* __restrict__ b1,
    const float* __restrict__ g2, const float* __restrict__ b2,
    float* __restrict__ XO, unsigned short* __restrict__ Xb)
{
  const long long row = blockIdx.x;
  const int t = threadIdx.x;
  const float s = invD[row];
  float v0 = X[row*EMB + t]       + SA[row*EMB + t]*s;
  float v1 = X[row*EMB + t + 256] + SA[row*EMB + t + 256]*s;
  float2 ss = block_sum2(v0+v1, v0*v0+v1*v1);
  float mean = ss.x*(1.f/EMB);
  float var  = ss.y*(1.f/EMB) - mean*mean;
  float rstd = rsqrtf(var + LNEPS);
  float y0 = (v0-mean)*rstd*g1[t]     + b1[t];
  float y1 = (v1-mean)*rstd*g1[t+256] + b1[t+256];
  ss = block_sum2(y0+y1, y0*y0+y1*y1);
  mean = ss.x*(1.f/EMB);
  var  = ss.y*(1.f/EMB) - mean*mean;
  rstd = rsqrtf(var + LNEPS);
  float o0 = (y0-mean)*rstd*g2[t]     + b2[t];
  float o1 = (y1-mean)*rstd*g2[t+256] + b2[t+256];
  XO[row*EMB + t] = o0;       XO[row*EMB + t + 256] = o1;
  Xb[row*EMB + t] = f2bf(o0); Xb[row*EMB + t + 256] = f2bf(o1);
}

// ------- residual + LN; writes fp32 + bf16 + bf16-transposed -------
__global__ __launch_bounds__(256) void residual_ln(
    const float* __restrict__ X, const float* __restrict__ R,
    const float* __restrict__ g, const float* __restrict__ b,
    float* __restrict__ XO, unsigned short* __restrict__ Xb,
    unsigned short* __restrict__ XT)
{
  const long long row = blockIdx.x;
  const int t = threadIdx.x;
  float v0 = X[row*EMB + t]       + R[row*EMB + t];
  float v1 = X[row*EMB + t + 256] + R[row*EMB + t + 256];
  float2 ss = block_sum2(v0+v1, v0*v0+v1*v1);
  float mean = ss.x*(1.f/EMB);
  float var  = ss.y*(1.f/EMB) - mean*mean;
  float rstd = rsqrtf(var + LNEPS);
  float o0 = (v0-mean)*rstd*g[t]     + b[t];
  float o1 = (v1-mean)*rstd*g[t+256] + b[t+256];
  XO[row*EMB + t] = o0;       XO[row*EMB + t + 256] = o1;
  Xb[row*EMB + t] = f2bf(o0); Xb[row*EMB + t + 256] = f2bf(o1);
  XT[(long long)t*NROWS + row] = f2bf(o0);
  XT[(long long)(t+256)*NROWS + row] = f2bf(o1);
}

// ------- initial x -> X fp32 copy + bf16 + bf16-transposed -------
__global__ __launch_bounds__(256) void init_x(
    const float* __restrict__ in, float* __restrict__ XO,
    unsigned short* __restrict__ Xb, unsigned short* __restrict__ XT)
{
  const long long row = blockIdx.x;
  const int t = threadIdx.x;
  float v0 = in[row*EMB + t];
  float v1 = in[row*EMB + t + 256];
  XO[row*EMB + t] = v0;       XO[row*EMB + t + 256] = v1;
  Xb[row*EMB + t] = f2bf(v0); Xb[row*EMB + t + 256] = f2bf(v1);
  XT[(long long)t*NROWS + row] = f2bf(v0);
  XT[(long long)(t+256)*NROWS + row] = f2bf(v1);
}

// ------- fp32 -> bf16 convert (n multiple of 4) -------
__global__ __launch_bounds__(256) void cvt_bf16(
    const float* __restrict__ src, unsigned short* __restrict__ dst, long long n)
{
  long long i = ((long long)blockIdx.x*256 + threadIdx.x)*4;
  if(i < n){
    float4 v = *(const float4*)(src + i);
    ushort4 o = make_ushort4(f2bf(v.x), f2bf(v.y), f2bf(v.z), f2bf(v.w));
    *(ushort4*)(dst + i) = o;
  }
}

extern "C" void kernel_launch(void* const* d_in, const int* in_sizes, int n_in,
                              void* d_out, int out_size, void* d_ws, size_t ws_size,
                              hipStream_t stream)
{
  const float* x_in = (const float*)d_in[0];
  const float* Wqkv = (const float*)d_in[1];
  const float* bqkv = (const float*)d_in[2];
  const float* W1   = (const float*)d_in[3];
  const float* b1   = (const float*)d_in[4];
  const float* W2   = (const float*)d_in[5];
  const float* b2   = (const float*)d_in[6];
  const float* g1   = (const float*)d_in[7];
  const float* bt1  = (const float*)d_in[8];
  const float* g2   = (const float*)d_in[9];
  const float* bt2  = (const float*)d_in[10];
  const float* g3   = (const float*)d_in[11];
  const float* bt3  = (const float*)d_in[12];

  float* X = (float*)d_out;                               // [8192,512] fp32

  char* ws = (char*)d_ws;
  unsigned short* qkv    = (unsigned short*)(ws);                       // 16MB [8192,1024] bf16 (q,k only)
  unsigned short* hbuf   = (unsigned short*)(ws + ((size_t)16<<20));    // 32MB [8192,2048] bf16
  unsigned short* Wm     = (unsigned short*)(ws + ((size_t)48<<20));    // 16MB [8,1024,1024] bf16
  float*          tmp    = (float*)         (ws + ((size_t)64<<20));    // 16MB [8192,512] fp32
  unsigned short* Xb     = (unsigned short*)(ws + ((size_t)80<<20));    // 8MB  [8192,512] bf16
  unsigned short* XT     = (unsigned short*)(ws + ((size_t)88<<20));    // 8MB  [512,8192] bf16
  unsigned short* Wqkvb  = (unsigned short*)(ws + ((size_t)96<<20));    // 6MB
  unsigned short* W1b    = (unsigned short*)(ws + ((size_t)102<<20));   // 8MB
  unsigned short* W2b    = (unsigned short*)(ws + ((size_t)110<<20));   // 8MB
  float*          invd8  = (float*)         (ws + ((size_t)118<<20));   // 256KB [8,8,1024]
  float*          invDb  = (float*)         (ws + ((size_t)119<<20));   // 32KB  [8192]

  // weight conversions (same work every call)
  cvt_bf16<<<3072, 256, 0, stream>>>(Wqkv, Wqkvb, (long long)4*1536*EMB);
  cvt_bf16<<<4096, 256, 0, stream>>>(W1,   W1b,   (long long)4*FFD*EMB);
  cvt_bf16<<<4096, 256, 0, stream>>>(W2,   W2b,   (long long)4*EMB*FFD);
  init_x<<<NROWS, 256, 0, stream>>>(x_in, X, Xb, XT);

  for(int d=0; d<4; d++){
    // qk = X * Wqkv[0:1024]^T + bqkv   (V-projection never used by reference)
    gemm_bf16<true,false,true,false><<<dim3(8, 64, 1), 256, 0, stream>>>(
        Xb, Wqkvb + (size_t)d*1536*EMB, bqkv + (size_t)d*1536, qkv,
        EMB, EMB, EMB, 1024, 0, 0, 0);

    attn_pass1<<<dim3(32, NB), 256, 0, stream>>>(qkv, invd8);

    hipMemsetAsync(Wm, 0, (size_t)NB*SEQ*SEQ*2, stream);
    attn_pass2<<<dim3(32, NB), 256, 0, stream>>>(qkv, invd8, Wm, invDb);

    // sa = W @ x  (B operand = XT, causal K limit)
    gemm_bf16<false,false,false,true><<<dim3(4, 8, NB), 256, 0, stream>>>(
        Wm, XT, nullptr, tmp,
        SEQ, SEQ, NROWS, EMB,
        (long long)SEQ*SEQ, 1024, (long long)SEQ*EMB);

    // x = LN2(LN1(x + sa*invD))
    residual_ln2<<<NROWS, 256, 0, stream>>>(X, tmp, invDb,
        g1 + d*EMB, bt1 + d*EMB, g2 + d*EMB, bt2 + d*EMB, X, Xb);

    // h = relu(x*W1^T + b1)
    gemm_bf16<true,true,true,false><<<dim3(16, 64, 1), 256, 0, stream>>>(
        Xb, W1b + (size_t)d*FFD*EMB, b1 + (size_t)d*FFD, hbuf,
        EMB, EMB, EMB, FFD, 0, 0, 0);

    // ff = h*W2^T + b2
    gemm_bf16<false,false,true,false><<<dim3(4, 64, 1), 256, 0, stream>>>(
        hbuf, W2b + (size_t)d*EMB*FFD, b2 + (size_t)d*EMB, tmp,
        FFD, FFD, FFD, EMB, 0, 0, 0);

    // x = LN3(x + ff)  (+ bf16 and transposed copies for next layer)
    residual_ln<<<NROWS, 256, 0, stream>>>(X, tmp, g3 + d*EMB, bt3 + d*EMB, X, Xb, XT);
  }
}

// Round 3
// 1096.786 us; speedup vs baseline: 3.7907x; 1.3017x over previous
//
#include <hip/hip_runtime.h>

#define NB 8
#define SEQ 1024
#define EMB 512
#define FFD 2048
#define NROWS (NB*SEQ)   // 8192
#define LNEPS 1e-5f

typedef __bf16 bf16x8 __attribute__((ext_vector_type(8)));
typedef float f32x4 __attribute__((ext_vector_type(4)));

__device__ __forceinline__ unsigned short f2bf(float f){
  unsigned u = __builtin_bit_cast(unsigned, f);
  u += 0x7fffu + ((u>>16)&1u);
  return (unsigned short)(u>>16);
}
__device__ __forceinline__ bf16x8 ld_bf8(const unsigned short* p){
  return *(const bf16x8*)p;
}
__device__ __forceinline__ void async_copy16(const void* g, void* l){
  __builtin_amdgcn_global_load_lds((const __attribute__((address_space(1))) unsigned int*)g,
                                   (__attribute__((address_space(3))) unsigned int*)l,
                                   16, 0, 0);
}

// ---------------- block reductions (256 threads = 4 waves) ----------------
__device__ __forceinline__ float2 block_sum2(float a,float b){
  #pragma unroll
  for(int k=32;k>=1;k>>=1){ a += __shfl_xor(a,k,64); b += __shfl_xor(b,k,64); }
  __shared__ float sa[4], sb[4];
  int w = threadIdx.x>>6;
  __syncthreads();
  if((threadIdx.x&63)==0){ sa[w]=a; sb[w]=b; }
  __syncthreads();
  return make_float2(sa[0]+sa[1]+sa[2]+sa[3], sb[0]+sb[1]+sb[2]+sb[3]);
}

// ---------------- bf16 MFMA GEMM: C = A * B^T (+bias) ----------------
// A [M,K] bf16 lda; B [N,K] bf16 ldb. 128x128 tile, BK=32, 4 waves (2x2 of 64x64).
// CAUSAL: k-loop limited to m0+128. BIAS applied only when blockIdx.z==0
// (lets blockIdx.z act as a split-K index with partial outputs).
template<bool OUTBF16, bool RELU, bool BIAS, bool CAUSAL>
__global__ __launch_bounds__(256) void gemm_bf16(
    const unsigned short* __restrict__ Ag, const unsigned short* __restrict__ Bg,
    const float* __restrict__ bias, void* __restrict__ Cg,
    int K, int lda, int ldb, int ldc,
    long long strA, long long strB, long long strC)
{
  __shared__ unsigned short As[128*32];
  __shared__ unsigned short Bs[128*32];
  const unsigned short* Ab = Ag + blockIdx.z*strA;
  const unsigned short* Bb = Bg + blockIdx.z*strB;
  const int m0 = blockIdx.y*128, n0 = blockIdx.x*128;
  const int t = threadIdx.x;
  const int lane = t & 63, w = t >> 6;
  const int wy = w >> 1, wx = w & 1;
  const int q = lane >> 4, c = lane & 15;
  f32x4 acc[4][4] = {};
  const int kend = CAUSAL ? (m0 + 128) : K;
  const int srow = t >> 2, skoff = (t & 3) * 8;   // lds offset = 16*t (lane-contiguous)
  for(int k0 = 0; k0 < kend; k0 += 32){
    async_copy16(Ab + (long long)(m0 + srow)*lda + k0 + skoff,      As + srow*32 + skoff);
    async_copy16(Ab + (long long)(m0 + srow + 64)*lda + k0 + skoff, As + (srow+64)*32 + skoff);
    async_copy16(Bb + (long long)(n0 + srow)*ldb + k0 + skoff,      Bs + srow*32 + skoff);
    async_copy16(Bb + (long long)(n0 + srow + 64)*ldb + k0 + skoff, Bs + (srow+64)*32 + skoff);
    __syncthreads();
    bf16x8 af[4], bfr[4];
    #pragma unroll
    for(int fi=0; fi<4; fi++) af[fi]  = ld_bf8(As + (wy*64 + fi*16 + c)*32 + q*8);
    #pragma unroll
    for(int fj=0; fj<4; fj++) bfr[fj] = ld_bf8(Bs + (wx*64 + fj*16 + c)*32 + q*8);
    #pragma unroll
    for(int fi=0; fi<4; fi++)
      #pragma unroll
      for(int fj=0; fj<4; fj++)
        acc[fi][fj] = __builtin_amdgcn_mfma_f32_16x16x32_bf16(af[fi], bfr[fj], acc[fi][fj], 0,0,0);
    __syncthreads();
  }
  #pragma unroll
  for(int fi=0; fi<4; fi++){
    #pragma unroll
    for(int fj=0; fj<4; fj++){
      const int row = m0 + wy*64 + fi*16 + q*4;
      const int col = n0 + wx*64 + fj*16 + c;
      const float bv = (BIAS && blockIdx.z==0) ? bias[col] : 0.f;
      #pragma unroll
      for(int r=0; r<4; r++){
        float v = acc[fi][fj][r] + bv;
        if(RELU) v = fmaxf(v, 0.f);
        long long off = blockIdx.z*strC + (long long)(row+r)*ldc + col;
        if(OUTBF16) ((unsigned short*)Cg)[off] = f2bf(v);
        else        ((float*)Cg)[off] = v;
      }
    }
  }
}

// -------- attention pass 1: dsum[b,h,i] += sum_j exp(q_i.k_j / 8) --------
// GEMM-shaped: grid (8 j-tiles, 8 i-tiles, 64 bh), 128x128 tile, K=64.
__global__ __launch_bounds__(256) void qk_dsum(
    const unsigned short* __restrict__ qkv, float* __restrict__ dsum)
{
  __shared__ unsigned short As[128*32];
  __shared__ unsigned short Bs[128*32];
  const int bh = blockIdx.z, b = bh >> 3, h = bh & 7;
  const int i0 = blockIdx.y*128, j0 = blockIdx.x*128;
  const unsigned short* Ab = qkv + (long long)b*SEQ*1024 + h*64;
  const unsigned short* Bb = qkv + (long long)b*SEQ*1024 + 512 + h*64;
  const int t = threadIdx.x, lane = t & 63, w = t >> 6;
  const int wy = w >> 1, wx = w & 1, q = lane >> 4, c = lane & 15;
  f32x4 acc[4][4] = {};
  const int srow = t >> 2, skoff = (t & 3) * 8;
  #pragma unroll
  for(int k0 = 0; k0 < 64; k0 += 32){
    async_copy16(Ab + (long long)(i0 + srow)*1024 + k0 + skoff,      As + srow*32 + skoff);
    async_copy16(Ab + (long long)(i0 + srow + 64)*1024 + k0 + skoff, As + (srow+64)*32 + skoff);
    async_copy16(Bb + (long long)(j0 + srow)*1024 + k0 + skoff,      Bs + srow*32 + skoff);
    async_copy16(Bb + (long long)(j0 + srow + 64)*1024 + k0 + skoff, Bs + (srow+64)*32 + skoff);
    __syncthreads();
    bf16x8 af[4], bfr[4];
    #pragma unroll
    for(int fi=0; fi<4; fi++) af[fi]  = ld_bf8(As + (wy*64 + fi*16 + c)*32 + q*8);
    #pragma unroll
    for(int fj=0; fj<4; fj++) bfr[fj] = ld_bf8(Bs + (wx*64 + fj*16 + c)*32 + q*8);
    #pragma unroll
    for(int fi=0; fi<4; fi++)
      #pragma unroll
      for(int fj=0; fj<4; fj++)
        acc[fi][fj] = __builtin_amdgcn_mfma_f32_16x16x32_bf16(af[fi], bfr[fj], acc[fi][fj], 0,0,0);
    __syncthreads();
  }
  #pragma unroll
  for(int fi=0; fi<4; fi++){
    #pragma unroll
    for(int r=0; r<4; r++){
      float s = 0.f;
      #pragma unroll
      for(int fj=0; fj<4; fj++) s += __expf(acc[fi][fj][r]*0.125f);
      s += __shfl_xor(s,1,64); s += __shfl_xor(s,2,64);
      s += __shfl_xor(s,4,64); s += __shfl_xor(s,8,64);
      if(c == 0)
        atomicAdd(&dsum[(long long)bh*SEQ + i0 + wy*64 + fi*16 + q*4 + r], s);
    }
  }
}

// -------- attention pass 2: averaged A + pos/causal + 2nd softmax numerator --------
// 64x64 causal tiles, grid (136 tri-tiles, 8 b). Per head: K=64 micro-GEMM,
// at += exp(l/8)*inv8[h][i]. Epilogue: w = (j<=i)? exp(at+pos) : 0 -> Wm (bf16),
// row-sums atomicAdd -> Dsum2.
__global__ __launch_bounds__(256) void attn_w(
    const unsigned short* __restrict__ qkv, const float* __restrict__ dsum,
    unsigned short* __restrict__ Wm, float* __restrict__ Dsum2)
{
  __shared__ unsigned short As[64*32];
  __shared__ unsigned short Bs[64*32];
  __shared__ float inv8[8][64];
  const int b = blockIdx.y;
  int x = blockIdx.x;
  int it = 0;
  while((it+1)*(it+2)/2 <= x) ++it;
  const int jt = x - it*(it+1)/2;
  const int i0 = it*64, j0 = jt*64;
  const int t = threadIdx.x, lane = t & 63, w = t >> 6;
  const int q = lane >> 4, c = lane & 15;
  for(int u = t; u < 512; u += 256){
    int h = u >> 6, r = u & 63;
    inv8[h][r] = 1.f/(8.f*dsum[((long long)(b*8 + h))*SEQ + i0 + r]);
  }
  const unsigned short* Qb = qkv + (long long)b*SEQ*1024;
  const int srow = t >> 2, skoff = (t & 3) * 8;
  f32x4 at[4] = {};
  for(int h = 0; h < 8; h++){
    f32x4 l[4] = {};
    #pragma unroll
    for(int k0 = 0; k0 < 64; k0 += 32){
      __syncthreads();
      async_copy16(Qb + (long long)(i0 + srow)*1024 + h*64 + k0 + skoff,       As + srow*32 + skoff);
      async_copy16(Qb + (long long)(j0 + srow)*1024 + 512 + h*64 + k0 + skoff, Bs + srow*32 + skoff);
      __syncthreads();
      bf16x8 af = ld_bf8(As + (w*16 + c)*32 + q*8);
      bf16x8 bfr[4];
      #pragma unroll
      for(int fj=0; fj<4; fj++) bfr[fj] = ld_bf8(Bs + (fj*16 + c)*32 + q*8);
      #pragma unroll
      for(int fj=0; fj<4; fj++)
        l[fj] = __builtin_amdgcn_mfma_f32_16x16x32_bf16(af, bfr[fj], l[fj], 0,0,0);
    }
    #pragma unroll
    for(int r=0; r<4; r++){
      float iv = inv8[h][w*16 + q*4 + r];
      #pragma unroll
      for(int fj=0; fj<4; fj++)
        at[fj][r] += __expf(l[fj][r]*0.125f)*iv;
    }
  }
  float Dacc[4] = {};
  #pragma unroll
  for(int fj=0; fj<4; fj++){
    #pragma unroll
    for(int r=0; r<4; r++){
      const int i = i0 + w*16 + q*4 + r;
      const int j = j0 + fj*16 + c;
      float wv = 0.f;
      if(j <= i) wv = __expf(at[fj][r] + __expf((float)(j - i)*0.1f));
      Wm[((long long)(b*SEQ + i))*SEQ + j] = f2bf(wv);
      Dacc[r] += wv;
    }
  }
  #pragma unroll
  for(int r=0; r<4; r++){
    Dacc[r] += __shfl_xor(Dacc[r],1,64); Dacc[r] += __shfl_xor(Dacc[r],2,64);
    Dacc[r] += __shfl_xor(Dacc[r],4,64); Dacc[r] += __shfl_xor(Dacc[r],8,64);
    if(c == 0)
      atomicAdd(&Dsum2[(long long)b*SEQ + i0 + w*16 + q*4 + r], Dacc[r]);
  }
}

// ------- fused residual(+1/Dsum2 scale) + LN1 + LN2; writes fp32 + bf16 -------
__global__ __launch_bounds__(256) void residual_ln2(
    const float* __restrict__ X, const float* __restrict__ SA,
    const float* __restrict__ Dsum2,
    const float* __restrict__ g1, const float* __restrict__ b1,
    const float* __restrict__ g2, const float* __restrict__ b2,
    float* __restrict__ XO, unsigned short* __restrict__ Xb)
{
  const long long row = blockIdx.x;
  const int t = threadIdx.x;
  const float s = 1.f/Dsum2[row];
  float v0 = X[row*EMB + t]       + SA[row*EMB + t]*s;
  float v1 = X[row*EMB + t + 256] + SA[row*EMB + t + 256]*s;
  float2 ss = block_sum2(v0+v1, v0*v0+v1*v1);
  float mean = ss.x*(1.f/EMB);
  float var  = ss.y*(1.f/EMB) - mean*mean;
  float rstd = rsqrtf(var + LNEPS);
  float y0 = (v0-mean)*rstd*g1[t]     + b1[t];
  float y1 = (v1-mean)*rstd*g1[t+256] + b1[t+256];
  ss = block_sum2(y0+y1, y0*y0+y1*y1);
  mean = ss.x*(1.f/EMB);
  var  = ss.y*(1.f/EMB) - mean*mean;
  rstd = rsqrtf(var + LNEPS);
  float o0 = (y0-mean)*rstd*g2[t]     + b2[t];
  float o1 = (y1-mean)*rstd*g2[t+256] + b2[t+256];
  XO[row*EMB + t] = o0;       XO[row*EMB + t + 256] = o1;
  Xb[row*EMB + t] = f2bf(o0); Xb[row*EMB + t + 256] = f2bf(o1);
}

// ------- residual(2 partials) + LN; writes fp32 + bf16 + bf16-transposed -------
__global__ __launch_bounds__(256) void residual_ln(
    const float* __restrict__ X, const float* __restrict__ R1,
    const float* __restrict__ R2,
    const float* __restrict__ g, const float* __restrict__ b,
    float* __restrict__ XO, unsigned short* __restrict__ Xb,
    unsigned short* __restrict__ XT)
{
  const long long row = blockIdx.x;
  const int t = threadIdx.x;
  float v0 = X[row*EMB + t]       + R1[row*EMB + t]       + R2[row*EMB + t];
  float v1 = X[row*EMB + t + 256] + R1[row*EMB + t + 256] + R2[row*EMB + t + 256];
  float2 ss = block_sum2(v0+v1, v0*v0+v1*v1);
  float mean = ss.x*(1.f/EMB);
  float var  = ss.y*(1.f/EMB) - mean*mean;
  float rstd = rsqrtf(var + LNEPS);
  float o0 = (v0-mean)*rstd*g[t]     + b[t];
  float o1 = (v1-mean)*rstd*g[t+256] + b[t+256];
  XO[row*EMB + t] = o0;       XO[row*EMB + t + 256] = o1;
  Xb[row*EMB + t] = f2bf(o0); Xb[row*EMB + t + 256] = f2bf(o1);
  XT[(long long)t*NROWS + row] = f2bf(o0);
  XT[(long long)(t+256)*NROWS + row] = f2bf(o1);
}

// ------- initial x -> X fp32 copy + bf16 + bf16-transposed -------
__global__ __launch_bounds__(256) void init_x(
    const float* __restrict__ in, float* __restrict__ XO,
    unsigned short* __restrict__ Xb, unsigned short* __restrict__ XT)
{
  const long long row = blockIdx.x;
  const int t = threadIdx.x;
  float v0 = in[row*EMB + t];
  float v1 = in[row*EMB + t + 256];
  XO[row*EMB + t] = v0;       XO[row*EMB + t + 256] = v1;
  Xb[row*EMB + t] = f2bf(v0); Xb[row*EMB + t + 256] = f2bf(v1);
  XT[(long long)t*NROWS + row] = f2bf(v0);
  XT[(long long)(t+256)*NROWS + row] = f2bf(v1);
}

// ------- fp32 -> bf16 convert (n multiple of 4) -------
__global__ __launch_bounds__(256) void cvt_bf16(
    const float* __restrict__ src, unsigned short* __restrict__ dst, long long n)
{
  long long i = ((long long)blockIdx.x*256 + threadIdx.x)*4;
  if(i < n){
    float4 v = *(const float4*)(src + i);
    ushort4 o = make_ushort4(f2bf(v.x), f2bf(v.y), f2bf(v.z), f2bf(v.w));
    *(ushort4*)(dst + i) = o;
  }
}

extern "C" void kernel_launch(void* const* d_in, const int* in_sizes, int n_in,
                              void* d_out, int out_size, void* d_ws, size_t ws_size,
                              hipStream_t stream)
{
  const float* x_in = (const float*)d_in[0];
  const float* Wqkv = (const float*)d_in[1];
  const float* bqkv = (const float*)d_in[2];
  const float* W1   = (const float*)d_in[3];
  const float* b1   = (const float*)d_in[4];
  const float* W2   = (const float*)d_in[5];
  const float* b2   = (const float*)d_in[6];
  const float* g1   = (const float*)d_in[7];
  const float* bt1  = (const float*)d_in[8];
  const float* g2   = (const float*)d_in[9];
  const float* bt2  = (const float*)d_in[10];
  const float* g3   = (const float*)d_in[11];
  const float* bt3  = (const float*)d_in[12];

  float* X = (float*)d_out;                               // [8192,512] fp32

  char* ws = (char*)d_ws;
  unsigned short* qkv    = (unsigned short*)(ws);                       // 16MB [8192,1024] bf16 (q,k)
  unsigned short* hbuf   = (unsigned short*)(ws + ((size_t)16<<20));    // 32MB [8192,2048] bf16
  unsigned short* Wm     = (unsigned short*)(ws + ((size_t)48<<20));    // 16MB [8,1024,1024] bf16
  float*          tmp    = (float*)         (ws + ((size_t)64<<20));    // 16MB [8192,512] fp32 (sa / ffn2 part0)
  float*          tmp2   = (float*)         (ws + ((size_t)80<<20));    // 16MB ffn2 part1
  unsigned short* Xb     = (unsigned short*)(ws + ((size_t)96<<20));    // 8MB  [8192,512] bf16
  unsigned short* XT     = (unsigned short*)(ws + ((size_t)104<<20));   // 8MB  [512,8192] bf16
  unsigned short* Wqkvb  = (unsigned short*)(ws + ((size_t)112<<20));   // 6MB
  unsigned short* W1b    = (unsigned short*)(ws + ((size_t)118<<20));   // 8MB
  unsigned short* W2b    = (unsigned short*)(ws + ((size_t)126<<20));   // 8MB
  float*          dsum   = (float*)         (ws + ((size_t)134<<20));   // 256KB [8,8,1024]
  float*          Dsum2  = (float*)         (ws + ((size_t)134<<20) + (256<<10)); // 32KB [8192]

  // weight conversions (same work every call)
  cvt_bf16<<<3072, 256, 0, stream>>>(Wqkv, Wqkvb, (long long)4*1536*EMB);
  cvt_bf16<<<4096, 256, 0, stream>>>(W1,   W1b,   (long long)4*FFD*EMB);
  cvt_bf16<<<4096, 256, 0, stream>>>(W2,   W2b,   (long long)4*EMB*FFD);
  init_x<<<NROWS, 256, 0, stream>>>(x_in, X, Xb, XT);

  for(int d=0; d<4; d++){
    // zero dsum + Dsum2 (adjacent, one memset)
    hipMemsetAsync(dsum, 0, (256<<10) + (32<<10), stream);

    // qk = X * Wqkv[0:1024]^T + bqkv
    gemm_bf16<true,false,true,false><<<dim3(8, 64, 1), 256, 0, stream>>>(
        Xb, Wqkvb + (size_t)d*1536*EMB, bqkv + (size_t)d*1536, qkv,
        EMB, EMB, EMB, 1024, 0, 0, 0);

    // per-head full-row softmax denominators
    qk_dsum<<<dim3(8, 8, 64), 256, 0, stream>>>(qkv, dsum);

    // averaged A + causal/pos re-softmax numerator -> Wm, Dsum2
    attn_w<<<dim3(136, NB), 256, 0, stream>>>(qkv, dsum, Wm, Dsum2);

    // sa = W @ x  (B operand = XT, causal K limit)
    gemm_bf16<false,false,false,true><<<dim3(4, 8, NB), 256, 0, stream>>>(
        Wm, XT, nullptr, tmp,
        SEQ, SEQ, NROWS, EMB,
        (long long)SEQ*SEQ, 1024, (long long)SEQ*EMB);

    // x = LN2(LN1(x + sa/Dsum2))
    residual_ln2<<<NROWS, 256, 0, stream>>>(X, tmp, Dsum2,
        g1 + d*EMB, bt1 + d*EMB, g2 + d*EMB, bt2 + d*EMB, X, Xb);

    // h = relu(x*W1^T + b1)
    gemm_bf16<true,true,true,false><<<dim3(16, 64, 1), 256, 0, stream>>>(
        Xb, W1b + (size_t)d*FFD*EMB, b1 + (size_t)d*FFD, hbuf,
        EMB, EMB, EMB, FFD, 0, 0, 0);

    // ff = h*W2^T + b2, split-K=2 (partials tmp, tmp2; bias on z==0)
    gemm_bf16<false,false,true,false><<<dim3(4, 64, 2), 256, 0, stream>>>(
        hbuf, W2b + (size_t)d*EMB*FFD, b2 + (size_t)d*EMB, tmp,
        1024, FFD, FFD, EMB,
        1024, 1024, (long long)NROWS*EMB);

    // x = LN3(x + ff0 + ff1)
    residual_ln<<<NROWS, 256, 0, stream>>>(X, tmp, tmp2,
        g3 + d*EMB, bt3 + d*EMB, X, Xb, XT);
  }
}

// Round 4
// 997.307 us; speedup vs baseline: 4.1688x; 1.0997x over previous
//
#include <hip/hip_runtime.h>

#define NB 8
#define SEQ 1024
#define EMB 512
#define FFD 2048
#define NROWS (NB*SEQ)   // 8192
#define LNEPS 1e-5f

typedef __bf16 bf16x8 __attribute__((ext_vector_type(8)));
typedef float f32x4 __attribute__((ext_vector_type(4)));

__device__ __forceinline__ unsigned short f2bf(float f){
  unsigned u = __builtin_bit_cast(unsigned, f);
  u += 0x7fffu + ((u>>16)&1u);
  return (unsigned short)(u>>16);
}
__device__ __forceinline__ bf16x8 ld_bf8(const unsigned short* p){
  return *(const bf16x8*)p;
}
__device__ __forceinline__ void async_copy16(const void* g, void* l){
  __builtin_amdgcn_global_load_lds((const __attribute__((address_space(1))) unsigned int*)g,
                                   (__attribute__((address_space(3))) unsigned int*)l,
                                   16, 0, 0);
}

// ---------------- block reductions (256 threads = 4 waves) ----------------
__device__ __forceinline__ float2 block_sum2(float a,float b){
  #pragma unroll
  for(int k=32;k>=1;k>>=1){ a += __shfl_xor(a,k,64); b += __shfl_xor(b,k,64); }
  __shared__ float sa[4], sb[4];
  int w = threadIdx.x>>6;
  __syncthreads();
  if((threadIdx.x&63)==0){ sa[w]=a; sb[w]=b; }
  __syncthreads();
  return make_float2(sa[0]+sa[1]+sa[2]+sa[3], sb[0]+sb[1]+sb[2]+sb[3]);
}

// ---------------- bf16 MFMA GEMM: C = A * B^T (+bias) ----------------
// A [M,K] bf16 lda; B [N,K] bf16 ldb. Tile 128 x NT (NT=128 or 64), BK=32,
// 4 waves (2x2). CAUSAL: k-loop limited to m0+128. BIAS only on blockIdx.z==0
// (so z can act as split-K with partial outputs).
// LDS XOR swizzle: store global chunk (t&3)^((t>>3)&3) at LDS slot t&3;
// fragment read slot = q ^ ((c>>1)&3)  -> bank-conflict-free b128 reads.
template<bool OUTBF16, bool RELU, bool BIAS, bool CAUSAL, int NT>
__global__ __launch_bounds__(256) void gemm_bf16(
    const unsigned short* __restrict__ Ag, const unsigned short* __restrict__ Bg,
    const float* __restrict__ bias, void* __restrict__ Cg,
    int K, int lda, int ldb, int ldc,
    long long strA, long long strB, long long strC)
{
  constexpr int NJ = NT/32;
  __shared__ unsigned short As[128*32];
  __shared__ unsigned short Bs[NT*32];
  const unsigned short* Ab = Ag + blockIdx.z*strA;
  const unsigned short* Bb = Bg + blockIdx.z*strB;
  const int m0 = blockIdx.y*128, n0 = blockIdx.x*NT;
  const int t = threadIdx.x;
  const int lane = t & 63, w = t >> 6;
  const int wy = w >> 1, wx = w & 1;
  const int q = lane >> 4, c = lane & 15;
  f32x4 acc[4][NJ] = {};
  const int kend = CAUSAL ? (m0 + 128) : K;
  const int srow = t >> 2;
  const int sk = (t & 3) * 8;                       // LDS chunk (HW-forced lane order)
  const int gk = ((t & 3) ^ ((t >> 3) & 3)) * 8;    // swizzled global chunk
  const int rs = (q ^ ((c >> 1) & 3)) * 8;          // swizzled read chunk
  for(int k0 = 0; k0 < kend; k0 += 32){
    async_copy16(Ab + (long long)(m0 + srow)*lda + k0 + gk,      As + srow*32 + sk);
    async_copy16(Ab + (long long)(m0 + srow + 64)*lda + k0 + gk, As + (srow+64)*32 + sk);
    async_copy16(Bb + (long long)(n0 + srow)*ldb + k0 + gk,      Bs + srow*32 + sk);
    if(NT == 128)
      async_copy16(Bb + (long long)(n0 + srow + 64)*ldb + k0 + gk, Bs + (srow+64)*32 + sk);
    __syncthreads();
    bf16x8 af[4], bfr[NJ];
    #pragma unroll
    for(int fi=0; fi<4; fi++) af[fi]  = ld_bf8(As + (wy*64 + fi*16 + c)*32 + rs);
    #pragma unroll
    for(int fj=0; fj<NJ; fj++) bfr[fj] = ld_bf8(Bs + (wx*(NT/2) + fj*16 + c)*32 + rs);
    #pragma unroll
    for(int fi=0; fi<4; fi++)
      #pragma unroll
      for(int fj=0; fj<NJ; fj++)
        acc[fi][fj] = __builtin_amdgcn_mfma_f32_16x16x32_bf16(af[fi], bfr[fj], acc[fi][fj], 0,0,0);
    __syncthreads();
  }
  #pragma unroll
  for(int fi=0; fi<4; fi++){
    #pragma unroll
    for(int fj=0; fj<NJ; fj++){
      const int row = m0 + wy*64 + fi*16 + q*4;
      const int col = n0 + wx*(NT/2) + fj*16 + c;
      const float bv = (BIAS && blockIdx.z==0) ? bias[col] : 0.f;
      #pragma unroll
      for(int r=0; r<4; r++){
        float v = acc[fi][fj][r] + bv;
        if(RELU) v = fmaxf(v, 0.f);
        long long off = blockIdx.z*strC + (long long)(row+r)*ldc + col;
        if(OUTBF16) ((unsigned short*)Cg)[off] = f2bf(v);
        else        ((float*)Cg)[off] = v;
      }
    }
  }
}

// -------- attention pass 1: dsum[b,h,i] += sum_j exp(q_i.k_j / 8) --------
// GEMM-shaped: grid (8 j-tiles, 8 i-tiles, 64 bh), 128x128 tile, K=64.
__global__ __launch_bounds__(256) void qk_dsum(
    const unsigned short* __restrict__ qkv, float* __restrict__ dsum)
{
  __shared__ unsigned short As[128*32];
  __shared__ unsigned short Bs[128*32];
  const int bh = blockIdx.z, b = bh >> 3, h = bh & 7;
  const int i0 = blockIdx.y*128, j0 = blockIdx.x*128;
  const unsigned short* Ab = qkv + (long long)b*SEQ*1024 + h*64;
  const unsigned short* Bb = qkv + (long long)b*SEQ*1024 + 512 + h*64;
  const int t = threadIdx.x, lane = t & 63, w = t >> 6;
  const int wy = w >> 1, wx = w & 1, q = lane >> 4, c = lane & 15;
  f32x4 acc[4][4] = {};
  const int srow = t >> 2;
  const int sk = (t & 3) * 8;
  const int gk = ((t & 3) ^ ((t >> 3) & 3)) * 8;
  const int rs = (q ^ ((c >> 1) & 3)) * 8;
  #pragma unroll
  for(int k0 = 0; k0 < 64; k0 += 32){
    async_copy16(Ab + (long long)(i0 + srow)*1024 + k0 + gk,      As + srow*32 + sk);
    async_copy16(Ab + (long long)(i0 + srow + 64)*1024 + k0 + gk, As + (srow+64)*32 + sk);
    async_copy16(Bb + (long long)(j0 + srow)*1024 + k0 + gk,      Bs + srow*32 + sk);
    async_copy16(Bb + (long long)(j0 + srow + 64)*1024 + k0 + gk, Bs + (srow+64)*32 + sk);
    __syncthreads();
    bf16x8 af[4], bfr[4];
    #pragma unroll
    for(int fi=0; fi<4; fi++) af[fi]  = ld_bf8(As + (wy*64 + fi*16 + c)*32 + rs);
    #pragma unroll
    for(int fj=0; fj<4; fj++) bfr[fj] = ld_bf8(Bs + (wx*64 + fj*16 + c)*32 + rs);
    #pragma unroll
    for(int fi=0; fi<4; fi++)
      #pragma unroll
      for(int fj=0; fj<4; fj++)
        acc[fi][fj] = __builtin_amdgcn_mfma_f32_16x16x32_bf16(af[fi], bfr[fj], acc[fi][fj], 0,0,0);
    __syncthreads();
  }
  #pragma unroll
  for(int fi=0; fi<4; fi++){
    #pragma unroll
    for(int r=0; r<4; r++){
      float s = 0.f;
      #pragma unroll
      for(int fj=0; fj<4; fj++) s += __expf(acc[fi][fj][r]*0.125f);
      s += __shfl_xor(s,1,64); s += __shfl_xor(s,2,64);
      s += __shfl_xor(s,4,64); s += __shfl_xor(s,8,64);
      if(c == 0)
        atomicAdd(&dsum[(long long)bh*SEQ + i0 + wy*64 + fi*16 + q*4 + r], s);
    }
  }
}

// -------- attention pass 2: averaged A + pos/causal + 2nd softmax numerator --------
__global__ __launch_bounds__(256) void attn_w(
    const unsigned short* __restrict__ qkv, const float* __restrict__ dsum,
    unsigned short* __restrict__ Wm, float* __restrict__ Dsum2)
{
  __shared__ unsigned short As[64*32];
  __shared__ unsigned short Bs[64*32];
  __shared__ float inv8[8][64];
  const int b = blockIdx.y;
  int x = blockIdx.x;
  int it = 0;
  while((it+1)*(it+2)/2 <= x) ++it;
  const int jt = x - it*(it+1)/2;
  const int i0 = it*64, j0 = jt*64;
  const int t = threadIdx.x, lane = t & 63, w = t >> 6;
  const int q = lane >> 4, c = lane & 15;
  for(int u = t; u < 512; u += 256){
    int h = u >> 6, r = u & 63;
    inv8[h][r] = 1.f/(8.f*dsum[((long long)(b*8 + h))*SEQ + i0 + r]);
  }
  const unsigned short* Qb = qkv + (long long)b*SEQ*1024;
  const int srow = t >> 2;
  const int sk = (t & 3) * 8;
  const int gk = ((t & 3) ^ ((t >> 3) & 3)) * 8;
  const int rs = (q ^ ((c >> 1) & 3)) * 8;
  f32x4 at[4] = {};
  for(int h = 0; h < 8; h++){
    f32x4 l[4] = {};
    #pragma unroll
    for(int k0 = 0; k0 < 64; k0 += 32){
      __syncthreads();
      async_copy16(Qb + (long long)(i0 + srow)*1024 + h*64 + k0 + gk,       As + srow*32 + sk);
      async_copy16(Qb + (long long)(j0 + srow)*1024 + 512 + h*64 + k0 + gk, Bs + srow*32 + sk);
      __syncthreads();
      bf16x8 af = ld_bf8(As + (w*16 + c)*32 + rs);
      bf16x8 bfr[4];
      #pragma unroll
      for(int fj=0; fj<4; fj++) bfr[fj] = ld_bf8(Bs + (fj*16 + c)*32 + rs);
      #pragma unroll
      for(int fj=0; fj<4; fj++)
        l[fj] = __builtin_amdgcn_mfma_f32_16x16x32_bf16(af, bfr[fj], l[fj], 0,0,0);
    }
    #pragma unroll
    for(int r=0; r<4; r++){
      float iv = inv8[h][w*16 + q*4 + r];
      #pragma unroll
      for(int fj=0; fj<4; fj++)
        at[fj][r] += __expf(l[fj][r]*0.125f)*iv;
    }
  }
  float Dacc[4] = {};
  #pragma unroll
  for(int fj=0; fj<4; fj++){
    #pragma unroll
    for(int r=0; r<4; r++){
      const int i = i0 + w*16 + q*4 + r;
      const int j = j0 + fj*16 + c;
      float wv = 0.f;
      if(j <= i) wv = __expf(at[fj][r] + __expf((float)(j - i)*0.1f));
      Wm[((long long)(b*SEQ + i))*SEQ + j] = f2bf(wv);
      Dacc[r] += wv;
    }
  }
  #pragma unroll
  for(int r=0; r<4; r++){
    Dacc[r] += __shfl_xor(Dacc[r],1,64); Dacc[r] += __shfl_xor(Dacc[r],2,64);
    Dacc[r] += __shfl_xor(Dacc[r],4,64); Dacc[r] += __shfl_xor(Dacc[r],8,64);
    if(c == 0)
      atomicAdd(&Dsum2[(long long)b*SEQ + i0 + w*16 + q*4 + r], Dacc[r]);
  }
}

// ------- LDS-tiled transpose: Xb [8192,512] -> XT [512,8192] -------
__global__ __launch_bounds__(256) void transpose_bf16(
    const unsigned short* __restrict__ src, unsigned short* __restrict__ dst)
{
  __shared__ unsigned short tile[64*65];
  const int bx = blockIdx.x;   // col tile of src (0..7)
  const int by = blockIdx.y;   // row tile of src (0..127)
  const int t = threadIdx.x;
  #pragma unroll
  for(int p=0; p<2; p++){
    int idx = t + p*256;
    int r = idx >> 3, cc = (idx & 7)*8;
    alignas(16) unsigned short e[8];
    *(uint4*)e = *(const uint4*)(src + (long long)(by*64 + r)*512 + bx*64 + cc);
    #pragma unroll
    for(int u=0; u<8; u++) tile[r*65 + cc + u] = e[u];
  }
  __syncthreads();
  #pragma unroll
  for(int p=0; p<2; p++){
    int idx = t + p*256;
    int r2 = idx >> 3, c2 = (idx & 7)*8;
    alignas(16) unsigned short e[8];
    #pragma unroll
    for(int u=0; u<8; u++) e[u] = tile[(c2+u)*65 + r2];
    *(uint4*)(dst + (long long)(bx*64 + r2)*8192 + by*64 + c2) = *(const uint4*)e;
  }
}

// ------- fused residual(+1/Dsum2 scale) + LN1 + LN2; writes fp32 + bf16 -------
__global__ __launch_bounds__(256) void residual_ln2(
    const float* __restrict__ X, const float* __restrict__ SA,
    const float* __restrict__ Dsum2,
    const float* __restrict__ g1, const float* __restrict__ b1,
    const float* __restrict__ g2, const float* __restrict__ b2,
    float* __restrict__ XO, unsigned short* __restrict__ Xb)
{
  const long long row = blockIdx.x;
  const int t = threadIdx.x;
  const float s = 1.f/Dsum2[row];
  float v0 = X[row*EMB + t]       + SA[row*EMB + t]*s;
  float v1 = X[row*EMB + t + 256] + SA[row*EMB + t + 256]*s;
  float2 ss = block_sum2(v0+v1, v0*v0+v1*v1);
  float mean = ss.x*(1.f/EMB);
  float var  = ss.y*(1.f/EMB) - mean*mean;
  float rstd = rsqrtf(var + LNEPS);
  float y0 = (v0-mean)*rstd*g1[t]     + b1[t];
  float y1 = (v1-mean)*rstd*g1[t+256] + b1[t+256];
  ss = block_sum2(y0+y1, y0*y0+y1*y1);
  mean = ss.x*(1.f/EMB);
  var  = ss.y*(1.f/EMB) - mean*mean;
  rstd = rsqrtf(var + LNEPS);
  float o0 = (y0-mean)*rstd*g2[t]     + b2[t];
  float o1 = (y1-mean)*rstd*g2[t+256] + b2[t+256];
  XO[row*EMB + t] = o0;       XO[row*EMB + t + 256] = o1;
  Xb[row*EMB + t] = f2bf(o0); Xb[row*EMB + t + 256] = f2bf(o1);
}

// ------- residual(2 partials) + LN; writes fp32 + bf16 -------
__global__ __launch_bounds__(256) void residual_ln(
    const float* __restrict__ X, const float* __restrict__ R1,
    const float* __restrict__ R2,
    const float* __restrict__ g, const float* __restrict__ b,
    float* __restrict__ XO, unsigned short* __restrict__ Xb)
{
  const long long row = blockIdx.x;
  const int t = threadIdx.x;
  float v0 = X[row*EMB + t]       + R1[row*EMB + t]       + R2[row*EMB + t];
  float v1 = X[row*EMB + t + 256] + R1[row*EMB + t + 256] + R2[row*EMB + t + 256];
  float2 ss = block_sum2(v0+v1, v0*v0+v1*v1);
  float mean = ss.x*(1.f/EMB);
  float var  = ss.y*(1.f/EMB) - mean*mean;
  float rstd = rsqrtf(var + LNEPS);
  float o0 = (v0-mean)*rstd*g[t]     + b[t];
  float o1 = (v1-mean)*rstd*g[t+256] + b[t+256];
  XO[row*EMB + t] = o0;       XO[row*EMB + t + 256] = o1;
  Xb[row*EMB + t] = f2bf(o0); Xb[row*EMB + t + 256] = f2bf(o1);
}

// ------- initial x -> X fp32 copy + bf16 -------
__global__ __launch_bounds__(256) void init_x(
    const float* __restrict__ in, float* __restrict__ XO,
    unsigned short* __restrict__ Xb)
{
  const long long row = blockIdx.x;
  const int t = threadIdx.x;
  float v0 = in[row*EMB + t];
  float v1 = in[row*EMB + t + 256];
  XO[row*EMB + t] = v0;       XO[row*EMB + t + 256] = v1;
  Xb[row*EMB + t] = f2bf(v0); Xb[row*EMB + t + 256] = f2bf(v1);
}

// ------- fp32 -> bf16 convert (n multiple of 4) -------
__global__ __launch_bounds__(256) void cvt_bf16(
    const float* __restrict__ src, unsigned short* __restrict__ dst, long long n)
{
  long long i = ((long long)blockIdx.x*256 + threadIdx.x)*4;
  if(i < n){
    float4 v = *(const float4*)(src + i);
    ushort4 o = make_ushort4(f2bf(v.x), f2bf(v.y), f2bf(v.z), f2bf(v.w));
    *(ushort4*)(dst + i) = o;
  }
}

// ------- Wqkv fp32 -> bf16, q/k rows only (first 1024 of each 1536) -------
__global__ __launch_bounds__(256) void cvt_qkv(
    const float* __restrict__ src, unsigned short* __restrict__ dst)
{
  long long i = ((long long)blockIdx.x*256 + threadIdx.x)*4;   // over 4*1024*512
  int layer = (int)(i >> 19);
  long long within = i & ((1LL<<19)-1);
  float4 v = *(const float4*)(src + (long long)layer*1536*512 + within);
  ushort4 o = make_ushort4(f2bf(v.x), f2bf(v.y), f2bf(v.z), f2bf(v.w));
  *(ushort4*)(dst + i) = o;
}

extern "C" void kernel_launch(void* const* d_in, const int* in_sizes, int n_in,
                              void* d_out, int out_size, void* d_ws, size_t ws_size,
                              hipStream_t stream)
{
  const float* x_in = (const float*)d_in[0];
  const float* Wqkv = (const float*)d_in[1];
  const float* bqkv = (const float*)d_in[2];
  const float* W1   = (const float*)d_in[3];
  const float* b1   = (const float*)d_in[4];
  const float* W2   = (const float*)d_in[5];
  const float* b2   = (const float*)d_in[6];
  const float* g1   = (const float*)d_in[7];
  const float* bt1  = (const float*)d_in[8];
  const float* g2   = (const float*)d_in[9];
  const float* bt2  = (const float*)d_in[10];
  const float* g3   = (const float*)d_in[11];
  const float* bt3  = (const float*)d_in[12];

  float* X = (float*)d_out;                               // [8192,512] fp32

  char* ws = (char*)d_ws;
  unsigned short* qkv    = (unsigned short*)(ws);                       // 16MB [8192,1024] bf16 (q,k)
  unsigned short* hbuf   = (unsigned short*)(ws + ((size_t)16<<20));    // 32MB [8192,2048] bf16
  unsigned short* Wm     = (unsigned short*)(ws + ((size_t)48<<20));    // 16MB [8,1024,1024] bf16
  float*          tmp    = (float*)         (ws + ((size_t)64<<20));    // 16MB [8192,512] fp32 (sa / ffn2 p0)
  float*          tmp2   = (float*)         (ws + ((size_t)80<<20));    // 16MB ffn2 p1
  unsigned short* Xb     = (unsigned short*)(ws + ((size_t)96<<20));    // 8MB  [8192,512] bf16
  unsigned short* XT     = (unsigned short*)(ws + ((size_t)104<<20));   // 8MB  [512,8192] bf16
  unsigned short* Wqkvb  = (unsigned short*)(ws + ((size_t)112<<20));   // 4MB  [4,1024,512]
  unsigned short* W1b    = (unsigned short*)(ws + ((size_t)118<<20));   // 8MB
  unsigned short* W2b    = (unsigned short*)(ws + ((size_t)126<<20));   // 8MB
  float*          dsum   = (float*)         (ws + ((size_t)134<<20));   // 256KB [8,8,1024]
  float*          Dsum2  = (float*)         (ws + ((size_t)134<<20) + (256<<10)); // 32KB [8192]

  // weight conversions (same work every call)
  cvt_qkv<<<2048, 256, 0, stream>>>(Wqkv, Wqkvb);
  cvt_bf16<<<4096, 256, 0, stream>>>(W1, W1b, (long long)4*FFD*EMB);
  cvt_bf16<<<4096, 256, 0, stream>>>(W2, W2b, (long long)4*EMB*FFD);
  init_x<<<NROWS, 256, 0, stream>>>(x_in, X, Xb);
  transpose_bf16<<<dim3(8,128), 256, 0, stream>>>(Xb, XT);

  for(int d=0; d<4; d++){
    hipMemsetAsync(dsum, 0, (256<<10) + (32<<10), stream);

    // qk = X * Wqkv[0:1024]^T + bqkv
    gemm_bf16<true,false,true,false,128><<<dim3(8, 64, 1), 256, 0, stream>>>(
        Xb, Wqkvb + (size_t)d*1024*EMB, bqkv + (size_t)d*1536, qkv,
        EMB, EMB, EMB, 1024, 0, 0, 0);

    // per-head full-row softmax denominators
    qk_dsum<<<dim3(8, 8, 64), 256, 0, stream>>>(qkv, dsum);

    // averaged A + causal/pos re-softmax numerator -> Wm, Dsum2
    attn_w<<<dim3(136, NB), 256, 0, stream>>>(qkv, dsum, Wm, Dsum2);

    // sa = W @ x  (B = XT per batch, causal K limit), 128x64 tiles
    gemm_bf16<false,false,false,true,64><<<dim3(8, 8, NB), 256, 0, stream>>>(
        Wm, XT, nullptr, tmp,
        SEQ, SEQ, NROWS, EMB,
        (long long)SEQ*SEQ, 1024, (long long)SEQ*EMB);

    // x = LN2(LN1(x + sa/Dsum2))
    residual_ln2<<<NROWS, 256, 0, stream>>>(X, tmp, Dsum2,
        g1 + d*EMB, bt1 + d*EMB, g2 + d*EMB, bt2 + d*EMB, X, Xb);

    // h = relu(x*W1^T + b1)
    gemm_bf16<true,true,true,false,128><<<dim3(16, 64, 1), 256, 0, stream>>>(
        Xb, W1b + (size_t)d*FFD*EMB, b1 + (size_t)d*FFD, hbuf,
        EMB, EMB, EMB, FFD, 0, 0, 0);

    // ff = h*W2^T + b2, split-K=2 (partials tmp, tmp2; bias on z==0)
    gemm_bf16<false,false,true,false,128><<<dim3(4, 64, 2), 256, 0, stream>>>(
        hbuf, W2b + (size_t)d*EMB*FFD, b2 + (size_t)d*EMB, tmp,
        1024, FFD, FFD, EMB,
        1024, 1024, (long long)NROWS*EMB);

    // x = LN3(x + ff0 + ff1)
    residual_ln<<<NROWS, 256, 0, stream>>>(X, tmp, tmp2,
        g3 + d*EMB, bt3 + d*EMB, X, Xb);
    transpose_bf16<<<dim3(8,128), 256, 0, stream>>>(Xb, XT);
  }
}

// Round 6
// 967.966 us; speedup vs baseline: 4.2951x; 1.0303x over previous
//
#include <hip/hip_runtime.h>

#define NB 8
#define SEQ 1024
#define EMB 512
#define FFD 2048
#define NROWS (NB*SEQ)   // 8192
#define LNEPS 1e-5f

typedef __bf16 bf16x8 __attribute__((ext_vector_type(8)));
typedef float f32x4 __attribute__((ext_vector_type(4)));

__device__ __forceinline__ unsigned short f2bf(float f){
  unsigned u = __builtin_bit_cast(unsigned, f);
  u += 0x7fffu + ((u>>16)&1u);
  return (unsigned short)(u>>16);
}
__device__ __forceinline__ bf16x8 ld_bf8(const unsigned short* p){
  return *(const bf16x8*)p;
}
__device__ __forceinline__ void async_copy16(const void* g, void* l){
  __builtin_amdgcn_global_load_lds((const __attribute__((address_space(1))) unsigned int*)g,
                                   (__attribute__((address_space(3))) unsigned int*)l,
                                   16, 0, 0);
}

// ---------------- block reductions (256 threads = 4 waves) ----------------
__device__ __forceinline__ float2 block_sum2(float a,float b){
  #pragma unroll
  for(int k=32;k>=1;k>>=1){ a += __shfl_xor(a,k,64); b += __shfl_xor(b,k,64); }
  __shared__ float sa[4], sb[4];
  int w = threadIdx.x>>6;
  __syncthreads();
  if((threadIdx.x&63)==0){ sa[w]=a; sb[w]=b; }
  __syncthreads();
  return make_float2(sa[0]+sa[1]+sa[2]+sa[3], sb[0]+sb[1]+sb[2]+sb[3]);
}

// ======== big-tile dbuf GEMM: C = A * B^T (+bias), 256x128 tile ========
// 512 threads = 8 waves (4x2 of 64x64). BK=32, double-buffered LDS (48KB),
// ONE barrier per K-iter: prefetch of k+1 issued post-barrier, lands during
// compute of k. BIAS only on blockIdx.z==0 (z = split-K index).
// NOTE global_load_lds LDS dest must be wave-uniform base + lane*16B:
// every staging call uses LDS element offset 8*t (+const) — legal pattern.
template<bool OUTBF16, bool RELU, bool BIAS>
__global__ __launch_bounds__(512,2) void gemm_big(
    const unsigned short* __restrict__ Ag, const unsigned short* __restrict__ Bg,
    const float* __restrict__ bias, void* __restrict__ Cg,
    int K, int lda, int ldb, int ldc,
    long long strA, long long strB, long long strC)
{
  __shared__ unsigned short As[2][256*32];
  __shared__ unsigned short Bs[2][128*32];
  const unsigned short* Ab = Ag + blockIdx.z*strA;
  const unsigned short* Bb = Bg + blockIdx.z*strB;
  const int m0 = blockIdx.y*256, n0 = blockIdx.x*128;
  const int t = threadIdx.x;
  const int lane = t & 63, w = t >> 6;
  const int wy = w >> 1, wx = w & 1;
  const int q = lane >> 4, c = lane & 15;
  // staging: chunk f=t -> rows 0..127 at LDS 8t; f=512+t -> rows 128..255 at
  // LDS 4096+8t; B chunk f=t -> LDS 8t. Same XOR swizzle both rounds
  // ((512+t)>>3 & 3 == (t>>3)&3 since 512 % 32 == 0).
  const int rA = t >> 2;
  const int gk = (((t & 3) ^ ((t >> 3) & 3)))*8;   // swizzled global chunk
  const int sO = t*8;                              // LDS element offset (lane*16B)
  const int rs = (q ^ ((c >> 1) & 3)) * 8;         // swizzled read chunk
  f32x4 acc[4][4] = {};

#define STAGE(bi, kk) do { \
    async_copy16(Ab + (long long)(m0 + rA)*lda + (kk) + gk,       &As[bi][sO]); \
    async_copy16(Ab + (long long)(m0 + 128 + rA)*lda + (kk) + gk, &As[bi][4096 + sO]); \
    async_copy16(Bb + (long long)(n0 + rA)*ldb + (kk) + gk,       &Bs[bi][sO]); \
  } while(0)

  STAGE(0, 0);
  int buf = 0;
  for(int k0 = 0; k0 < K; k0 += 32, buf ^= 1){
    __syncthreads();                       // drains prefetch of `buf`; fences reads of buf^1
    if(k0 + 32 < K) STAGE(buf^1, k0 + 32); // lands during compute below
    bf16x8 af[4], bfr[4];
    #pragma unroll
    for(int fi=0; fi<4; fi++) af[fi]  = ld_bf8(&As[buf][(wy*64 + fi*16 + c)*32 + rs]);
    #pragma unroll
    for(int fj=0; fj<4; fj++) bfr[fj] = ld_bf8(&Bs[buf][(wx*64 + fj*16 + c)*32 + rs]);
    #pragma unroll
    for(int fi=0; fi<4; fi++)
      #pragma unroll
      for(int fj=0; fj<4; fj++)
        acc[fi][fj] = __builtin_amdgcn_mfma_f32_16x16x32_bf16(af[fi], bfr[fj], acc[fi][fj], 0,0,0);
  }
#undef STAGE
  #pragma unroll
  for(int fi=0; fi<4; fi++){
    #pragma unroll
    for(int fj=0; fj<4; fj++){
      const int row = m0 + wy*64 + fi*16 + q*4;
      const int col = n0 + wx*64 + fj*16 + c;
      const float bv = (BIAS && blockIdx.z==0) ? bias[col] : 0.f;
      #pragma unroll
      for(int r=0; r<4; r++){
        float v = acc[fi][fj][r] + bv;
        if(RELU) v = fmaxf(v, 0.f);
        long long off = blockIdx.z*strC + (long long)(row+r)*ldc + col;
        if(OUTBF16) ((unsigned short*)Cg)[off] = f2bf(v);
        else        ((float*)Cg)[off] = v;
      }
    }
  }
}

// ---------------- 128-tile GEMM (kept for causal sa): C = A * B^T ----------------
template<bool OUTBF16, bool RELU, bool BIAS, bool CAUSAL, int NT>
__global__ __launch_bounds__(256) void gemm_bf16(
    const unsigned short* __restrict__ Ag, const unsigned short* __restrict__ Bg,
    const float* __restrict__ bias, void* __restrict__ Cg,
    int K, int lda, int ldb, int ldc,
    long long strA, long long strB, long long strC)
{
  constexpr int NJ = NT/32;
  __shared__ unsigned short As[128*32];
  __shared__ unsigned short Bs[NT*32];
  const unsigned short* Ab = Ag + blockIdx.z*strA;
  const unsigned short* Bb = Bg + blockIdx.z*strB;
  const int m0 = blockIdx.y*128, n0 = blockIdx.x*NT;
  const int t = threadIdx.x;
  const int lane = t & 63, w = t >> 6;
  const int wy = w >> 1, wx = w & 1;
  const int q = lane >> 4, c = lane & 15;
  f32x4 acc[4][NJ] = {};
  const int kend = CAUSAL ? (m0 + 128) : K;
  const int srow = t >> 2;
  const int sk = (t & 3) * 8;
  const int gk = ((t & 3) ^ ((t >> 3) & 3)) * 8;
  const int rs = (q ^ ((c >> 1) & 3)) * 8;
  for(int k0 = 0; k0 < kend; k0 += 32){
    async_copy16(Ab + (long long)(m0 + srow)*lda + k0 + gk,      As + srow*32 + sk);
    async_copy16(Ab + (long long)(m0 + srow + 64)*lda + k0 + gk, As + (srow+64)*32 + sk);
    async_copy16(Bb + (long long)(n0 + srow)*ldb + k0 + gk,      Bs + srow*32 + sk);
    if(NT == 128)
      async_copy16(Bb + (long long)(n0 + srow + 64)*ldb + k0 + gk, Bs + (srow+64)*32 + sk);
    __syncthreads();
    bf16x8 af[4], bfr[NJ];
    #pragma unroll
    for(int fi=0; fi<4; fi++) af[fi]  = ld_bf8(As + (wy*64 + fi*16 + c)*32 + rs);
    #pragma unroll
    for(int fj=0; fj<NJ; fj++) bfr[fj] = ld_bf8(Bs + (wx*(NT/2) + fj*16 + c)*32 + rs);
    #pragma unroll
    for(int fi=0; fi<4; fi++)
      #pragma unroll
      for(int fj=0; fj<NJ; fj++)
        acc[fi][fj] = __builtin_amdgcn_mfma_f32_16x16x32_bf16(af[fi], bfr[fj], acc[fi][fj], 0,0,0);
    __syncthreads();
  }
  #pragma unroll
  for(int fi=0; fi<4; fi++){
    #pragma unroll
    for(int fj=0; fj<NJ; fj++){
      const int row = m0 + wy*64 + fi*16 + q*4;
      const int col = n0 + wx*(NT/2) + fj*16 + c;
      const float bv = (BIAS && blockIdx.z==0) ? bias[col] : 0.f;
      #pragma unroll
      for(int r=0; r<4; r++){
        float v = acc[fi][fj][r] + bv;
        if(RELU) v = fmaxf(v, 0.f);
        long long off = blockIdx.z*strC + (long long)(row+r)*ldc + col;
        if(OUTBF16) ((unsigned short*)Cg)[off] = f2bf(v);
        else        ((float*)Cg)[off] = v;
      }
    }
  }
}

// -------- attention pass 1: dsum[b,h,i] += sum_j exp(q_i.k_j / 8) --------
__global__ __launch_bounds__(256) void qk_dsum(
    const unsigned short* __restrict__ qkv, float* __restrict__ dsum)
{
  __shared__ unsigned short As[128*32];
  __shared__ unsigned short Bs[128*32];
  const int bh = blockIdx.z, b = bh >> 3, h = bh & 7;
  const int i0 = blockIdx.y*128, j0 = blockIdx.x*128;
  const unsigned short* Ab = qkv + (long long)b*SEQ*1024 + h*64;
  const unsigned short* Bb = qkv + (long long)b*SEQ*1024 + 512 + h*64;
  const int t = threadIdx.x, lane = t & 63, w = t >> 6;
  const int wy = w >> 1, wx = w & 1, q = lane >> 4, c = lane & 15;
  f32x4 acc[4][4] = {};
  const int srow = t >> 2;
  const int sk = (t & 3) * 8;
  const int gk = ((t & 3) ^ ((t >> 3) & 3)) * 8;
  const int rs = (q ^ ((c >> 1) & 3)) * 8;
  #pragma unroll
  for(int k0 = 0; k0 < 64; k0 += 32){
    async_copy16(Ab + (long long)(i0 + srow)*1024 + k0 + gk,      As + srow*32 + sk);
    async_copy16(Ab + (long long)(i0 + srow + 64)*1024 + k0 + gk, As + (srow+64)*32 + sk);
    async_copy16(Bb + (long long)(j0 + srow)*1024 + k0 + gk,      Bs + srow*32 + sk);
    async_copy16(Bb + (long long)(j0 + srow + 64)*1024 + k0 + gk, Bs + (srow+64)*32 + sk);
    __syncthreads();
    bf16x8 af[4], bfr[4];
    #pragma unroll
    for(int fi=0; fi<4; fi++) af[fi]  = ld_bf8(As + (wy*64 + fi*16 + c)*32 + rs);
    #pragma unroll
    for(int fj=0; fj<4; fj++) bfr[fj] = ld_bf8(Bs + (wx*64 + fj*16 + c)*32 + rs);
    #pragma unroll
    for(int fi=0; fi<4; fi++)
      #pragma unroll
      for(int fj=0; fj<4; fj++)
        acc[fi][fj] = __builtin_amdgcn_mfma_f32_16x16x32_bf16(af[fi], bfr[fj], acc[fi][fj], 0,0,0);
    __syncthreads();
  }
  #pragma unroll
  for(int fi=0; fi<4; fi++){
    #pragma unroll
    for(int r=0; r<4; r++){
      float s = 0.f;
      #pragma unroll
      for(int fj=0; fj<4; fj++) s += __expf(acc[fi][fj][r]*0.125f);
      s += __shfl_xor(s,1,64); s += __shfl_xor(s,2,64);
      s += __shfl_xor(s,4,64); s += __shfl_xor(s,8,64);
      if(c == 0)
        atomicAdd(&dsum[(long long)bh*SEQ + i0 + wy*64 + fi*16 + q*4 + r], s);
    }
  }
}

// -------- attention pass 2: averaged A + pos/causal + 2nd softmax numerator --------
__global__ __launch_bounds__(256) void attn_w(
    const unsigned short* __restrict__ qkv, const float* __restrict__ dsum,
    unsigned short* __restrict__ Wm, float* __restrict__ Dsum2)
{
  __shared__ unsigned short As[64*32];
  __shared__ unsigned short Bs[64*32];
  __shared__ float inv8[8][64];
  const int b = blockIdx.y;
  int x = blockIdx.x;
  int it = 0;
  while((it+1)*(it+2)/2 <= x) ++it;
  const int jt = x - it*(it+1)/2;
  const int i0 = it*64, j0 = jt*64;
  const int t = threadIdx.x, lane = t & 63, w = t >> 6;
  const int q = lane >> 4, c = lane & 15;
  for(int u = t; u < 512; u += 256){
    int h = u >> 6, r = u & 63;
    inv8[h][r] = 1.f/(8.f*dsum[((long long)(b*8 + h))*SEQ + i0 + r]);
  }
  const unsigned short* Qb = qkv + (long long)b*SEQ*1024;
  const int srow = t >> 2;
  const int sk = (t & 3) * 8;
  const int gk = ((t & 3) ^ ((t >> 3) & 3)) * 8;
  const int rs = (q ^ ((c >> 1) & 3)) * 8;
  f32x4 at[4] = {};
  for(int h = 0; h < 8; h++){
    f32x4 l[4] = {};
    #pragma unroll
    for(int k0 = 0; k0 < 64; k0 += 32){
      __syncthreads();
      async_copy16(Qb + (long long)(i0 + srow)*1024 + h*64 + k0 + gk,       As + srow*32 + sk);
      async_copy16(Qb + (long long)(j0 + srow)*1024 + 512 + h*64 + k0 + gk, Bs + srow*32 + sk);
      __syncthreads();
      bf16x8 af = ld_bf8(As + (w*16 + c)*32 + rs);
      bf16x8 bfr[4];
      #pragma unroll
      for(int fj=0; fj<4; fj++) bfr[fj] = ld_bf8(Bs + (fj*16 + c)*32 + rs);
      #pragma unroll
      for(int fj=0; fj<4; fj++)
        l[fj] = __builtin_amdgcn_mfma_f32_16x16x32_bf16(af, bfr[fj], l[fj], 0,0,0);
    }
    #pragma unroll
    for(int r=0; r<4; r++){
      float iv = inv8[h][w*16 + q*4 + r];
      #pragma unroll
      for(int fj=0; fj<4; fj++)
        at[fj][r] += __expf(l[fj][r]*0.125f)*iv;
    }
  }
  float Dacc[4] = {};
  #pragma unroll
  for(int fj=0; fj<4; fj++){
    #pragma unroll
    for(int r=0; r<4; r++){
      const int i = i0 + w*16 + q*4 + r;
      const int j = j0 + fj*16 + c;
      float wv = 0.f;
      if(j <= i) wv = __expf(at[fj][r] + __expf((float)(j - i)*0.1f));
      Wm[((long long)(b*SEQ + i))*SEQ + j] = f2bf(wv);
      Dacc[r] += wv;
    }
  }
  #pragma unroll
  for(int r=0; r<4; r++){
    Dacc[r] += __shfl_xor(Dacc[r],1,64); Dacc[r] += __shfl_xor(Dacc[r],2,64);
    Dacc[r] += __shfl_xor(Dacc[r],4,64); Dacc[r] += __shfl_xor(Dacc[r],8,64);
    if(c == 0)
      atomicAdd(&Dsum2[(long long)b*SEQ + i0 + w*16 + q*4 + r], Dacc[r]);
  }
}

// ------- LDS-tiled transpose: Xb [8192,512] -> XT [512,8192] -------
__global__ __launch_bounds__(256) void transpose_bf16(
    const unsigned short* __restrict__ src, unsigned short* __restrict__ dst)
{
  __shared__ unsigned short tile[64*65];
  const int bx = blockIdx.x;
  const int by = blockIdx.y;
  const int t = threadIdx.x;
  #pragma unroll
  for(int p=0; p<2; p++){
    int idx = t + p*256;
    int r = idx >> 3, cc = (idx & 7)*8;
    alignas(16) unsigned short e[8];
    *(uint4*)e = *(const uint4*)(src + (long long)(by*64 + r)*512 + bx*64 + cc);
    #pragma unroll
    for(int u=0; u<8; u++) tile[r*65 + cc + u] = e[u];
  }
  __syncthreads();
  #pragma unroll
  for(int p=0; p<2; p++){
    int idx = t + p*256;
    int r2 = idx >> 3, c2 = (idx & 7)*8;
    alignas(16) unsigned short e[8];
    #pragma unroll
    for(int u=0; u<8; u++) e[u] = tile[(c2+u)*65 + r2];
    *(uint4*)(dst + (long long)(bx*64 + r2)*8192 + by*64 + c2) = *(const uint4*)e;
  }
}

// ------- fused residual(+1/Dsum2 scale) + LN1 + LN2; writes fp32 + bf16 -------
__global__ __launch_bounds__(256) void residual_ln2(
    const float* __restrict__ X, const float* __restrict__ SA,
    const float* __restrict__ Dsum2,
    const float* __restrict__ g1, const float* __restrict__ b1,
    const float* __restrict__ g2, const float* __restrict__ b2,
    float* __restrict__ XO, unsigned short* __restrict__ Xb)
{
  const long long row = blockIdx.x;
  const int t = threadIdx.x;
  const float s = 1.f/Dsum2[row];
  float v0 = X[row*EMB + t]       + SA[row*EMB + t]*s;
  float v1 = X[row*EMB + t + 256] + SA[row*EMB + t + 256]*s;
  float2 ss = block_sum2(v0+v1, v0*v0+v1*v1);
  float mean = ss.x*(1.f/EMB);
  float var  = ss.y*(1.f/EMB) - mean*mean;
  float rstd = rsqrtf(var + LNEPS);
  float y0 = (v0-mean)*rstd*g1[t]     + b1[t];
  float y1 = (v1-mean)*rstd*g1[t+256] + b1[t+256];
  ss = block_sum2(y0+y1, y0*y0+y1*y1);
  mean = ss.x*(1.f/EMB);
  var  = ss.y*(1.f/EMB) - mean*mean;
  rstd = rsqrtf(var + LNEPS);
  float o0 = (y0-mean)*rstd*g2[t]     + b2[t];
  float o1 = (y1-mean)*rstd*g2[t+256] + b2[t+256];
  XO[row*EMB + t] = o0;       XO[row*EMB + t + 256] = o1;
  Xb[row*EMB + t] = f2bf(o0); Xb[row*EMB + t + 256] = f2bf(o1);
}

// ------- residual(2 partials) + LN; writes fp32 + bf16 -------
__global__ __launch_bounds__(256) void residual_ln(
    const float* __restrict__ X, const float* __restrict__ R1,
    const float* __restrict__ R2,
    const float* __restrict__ g, const float* __restrict__ b,
    float* __restrict__ XO, unsigned short* __restrict__ Xb)
{
  const long long row = blockIdx.x;
  const int t = threadIdx.x;
  float v0 = X[row*EMB + t]       + R1[row*EMB + t]       + R2[row*EMB + t];
  float v1 = X[row*EMB + t + 256] + R1[row*EMB + t + 256] + R2[row*EMB + t + 256];
  float2 ss = block_sum2(v0+v1, v0*v0+v1*v1);
  float mean = ss.x*(1.f/EMB);
  float var  = ss.y*(1.f/EMB) - mean*mean;
  float rstd = rsqrtf(var + LNEPS);
  float o0 = (v0-mean)*rstd*g[t]     + b[t];
  float o1 = (v1-mean)*rstd*g[t+256] + b[t+256];
  XO[row*EMB + t] = o0;       XO[row*EMB + t + 256] = o1;
  Xb[row*EMB + t] = f2bf(o0); Xb[row*EMB + t + 256] = f2bf(o1);
}

// ------- initial x -> X fp32 copy + bf16 -------
__global__ __launch_bounds__(256) void init_x(
    const float* __restrict__ in, float* __restrict__ XO,
    unsigned short* __restrict__ Xb)
{
  const long long row = blockIdx.x;
  const int t = threadIdx.x;
  float v0 = in[row*EMB + t];
  float v1 = in[row*EMB + t + 256];
  XO[row*EMB + t] = v0;       XO[row*EMB + t + 256] = v1;
  Xb[row*EMB + t] = f2bf(v0); Xb[row*EMB + t + 256] = f2bf(v1);
}

// ------- fp32 -> bf16 convert (n multiple of 4) -------
__global__ __launch_bounds__(256) void cvt_bf16(
    const float* __restrict__ src, unsigned short* __restrict__ dst, long long n)
{
  long long i = ((long long)blockIdx.x*256 + threadIdx.x)*4;
  if(i < n){
    float4 v = *(const float4*)(src + i);
    ushort4 o = make_ushort4(f2bf(v.x), f2bf(v.y), f2bf(v.z), f2bf(v.w));
    *(ushort4*)(dst + i) = o;
  }
}

// ------- Wqkv fp32 -> bf16, q/k rows only (first 1024 of each 1536) -------
__global__ __launch_bounds__(256) void cvt_qkv(
    const float* __restrict__ src, unsigned short* __restrict__ dst)
{
  long long i = ((long long)blockIdx.x*256 + threadIdx.x)*4;   // over 4*1024*512
  int layer = (int)(i >> 19);
  long long within = i & ((1LL<<19)-1);
  float4 v = *(const float4*)(src + (long long)layer*1536*512 + within);
  ushort4 o = make_ushort4(f2bf(v.x), f2bf(v.y), f2bf(v.z), f2bf(v.w));
  *(ushort4*)(dst + i) = o;
}

extern "C" void kernel_launch(void* const* d_in, const int* in_sizes, int n_in,
                              void* d_out, int out_size, void* d_ws, size_t ws_size,
                              hipStream_t stream)
{
  const float* x_in = (const float*)d_in[0];
  const float* Wqkv = (const float*)d_in[1];
  const float* bqkv = (const float*)d_in[2];
  const float* W1   = (const float*)d_in[3];
  const float* b1   = (const float*)d_in[4];
  const float* W2   = (const float*)d_in[5];
  const float* b2   = (const float*)d_in[6];
  const float* g1   = (const float*)d_in[7];
  const float* bt1  = (const float*)d_in[8];
  const float* g2   = (const float*)d_in[9];
  const float* bt2  = (const float*)d_in[10];
  const float* g3   = (const float*)d_in[11];
  const float* bt3  = (const float*)d_in[12];

  float* X = (float*)d_out;                               // [8192,512] fp32

  char* ws = (char*)d_ws;
  unsigned short* qkv    = (unsigned short*)(ws);                       // 16MB [8192,1024] bf16 (q,k)
  unsigned short* hbuf   = (unsigned short*)(ws + ((size_t)16<<20));    // 32MB [8192,2048] bf16
  unsigned short* Wm     = (unsigned short*)(ws + ((size_t)48<<20));    // 16MB [8,1024,1024] bf16
  float*          tmp    = (float*)         (ws + ((size_t)64<<20));    // 16MB [8192,512] fp32 (sa / ffn2 p0)
  float*          tmp2   = (float*)         (ws + ((size_t)80<<20));    // 16MB ffn2 p1 (contiguous after tmp!)
  unsigned short* Xb     = (unsigned short*)(ws + ((size_t)96<<20));    // 8MB  [8192,512] bf16
  unsigned short* XT     = (unsigned short*)(ws + ((size_t)104<<20));   // 8MB  [512,8192] bf16
  unsigned short* Wqkvb  = (unsigned short*)(ws + ((size_t)112<<20));   // 4MB  [4,1024,512]
  unsigned short* W1b    = (unsigned short*)(ws + ((size_t)118<<20));   // 8MB
  unsigned short* W2b    = (unsigned short*)(ws + ((size_t)126<<20));   // 8MB
  float*          dsum   = (float*)         (ws + ((size_t)134<<20));   // 256KB [8,8,1024]
  float*          Dsum2  = (float*)         (ws + ((size_t)134<<20) + (256<<10)); // 32KB [8192]

  // weight conversions (same work every call)
  cvt_qkv<<<2048, 256, 0, stream>>>(Wqkv, Wqkvb);
  cvt_bf16<<<4096, 256, 0, stream>>>(W1, W1b, (long long)4*FFD*EMB);
  cvt_bf16<<<4096, 256, 0, stream>>>(W2, W2b, (long long)4*EMB*FFD);
  init_x<<<NROWS, 256, 0, stream>>>(x_in, X, Xb);
  transpose_bf16<<<dim3(8,128), 256, 0, stream>>>(Xb, XT);

  for(int d=0; d<4; d++){
    hipMemsetAsync(dsum, 0, (256<<10) + (32<<10), stream);

    // qk = X * Wqkv[0:1024]^T + bqkv   (256x128 tiles, dbuf)
    gemm_big<true,false,true><<<dim3(8, 32, 1), 512, 0, stream>>>(
        Xb, Wqkvb + (size_t)d*1024*EMB, bqkv + (size_t)d*1536, qkv,
        EMB, EMB, EMB, 1024, 0, 0, 0);

    // per-head full-row softmax denominators
    qk_dsum<<<dim3(8, 8, 64), 256, 0, stream>>>(qkv, dsum);

    // averaged A + causal/pos re-softmax numerator -> Wm, Dsum2
    attn_w<<<dim3(136, NB), 256, 0, stream>>>(qkv, dsum, Wm, Dsum2);

    // sa = W @ x  (B = XT per batch, causal K limit), 128x64 tiles
    gemm_bf16<false,false,false,true,64><<<dim3(8, 8, NB), 256, 0, stream>>>(
        Wm, XT, nullptr, tmp,
        SEQ, SEQ, NROWS, EMB,
        (long long)SEQ*SEQ, 1024, (long long)SEQ*EMB);

    // x = LN2(LN1(x + sa/Dsum2))
    residual_ln2<<<NROWS, 256, 0, stream>>>(X, tmp, Dsum2,
        g1 + d*EMB, bt1 + d*EMB, g2 + d*EMB, bt2 + d*EMB, X, Xb);

    // h = relu(x*W1^T + b1)   (256x128 tiles, dbuf)
    gemm_big<true,true,true><<<dim3(16, 32, 1), 512, 0, stream>>>(
        Xb, W1b + (size_t)d*FFD*EMB, b1 + (size_t)d*FFD, hbuf,
        EMB, EMB, EMB, FFD, 0, 0, 0);

    // ff = h*W2^T + b2, split-K=2 (partials tmp, tmp2; bias on z==0)
    gemm_big<false,false,true><<<dim3(4, 32, 2), 512, 0, stream>>>(
        hbuf, W2b + (size_t)d*EMB*FFD, b2 + (size_t)d*EMB, tmp,
        1024, FFD, FFD, EMB,
        1024, 1024, (long long)NROWS*EMB);

    // x = LN3(x + ff0 + ff1)
    residual_ln<<<NROWS, 256, 0, stream>>>(X, tmp, tmp2,
        g3 + d*EMB, bt3 + d*EMB, X, Xb);
    transpose_bf16<<<dim3(8,128), 256, 0, stream>>>(Xb, XT);
  }
}

// Round 7
// 946.483 us; speedup vs baseline: 4.3926x; 1.0227x over previous
//
#include <hip/hip_runtime.h>

#define NB 8
#define SEQ 1024
#define EMB 512
#define FFD 2048
#define NROWS (NB*SEQ)   // 8192
#define LNEPS 1e-5f

typedef __bf16 bf16x8 __attribute__((ext_vector_type(8)));
typedef float f32x4 __attribute__((ext_vector_type(4)));

__device__ __forceinline__ unsigned short f2bf(float f){
  unsigned u = __builtin_bit_cast(unsigned, f);
  u += 0x7fffu + ((u>>16)&1u);
  return (unsigned short)(u>>16);
}
__device__ __forceinline__ bf16x8 ld_bf8(const unsigned short* p){
  return *(const bf16x8*)p;
}
__device__ __forceinline__ void async_copy16(const void* g, void* l){
  __builtin_amdgcn_global_load_lds((const __attribute__((address_space(1))) unsigned int*)g,
                                   (__attribute__((address_space(3))) unsigned int*)l,
                                   16, 0, 0);
}

// ---------------- block reductions (256 threads = 4 waves) ----------------
__device__ __forceinline__ float2 block_sum2(float a,float b){
  #pragma unroll
  for(int k=32;k>=1;k>>=1){ a += __shfl_xor(a,k,64); b += __shfl_xor(b,k,64); }
  __shared__ float sa[4], sb[4];
  int w = threadIdx.x>>6;
  __syncthreads();
  if((threadIdx.x&63)==0){ sa[w]=a; sb[w]=b; }
  __syncthreads();
  return make_float2(sa[0]+sa[1]+sa[2]+sa[3], sb[0]+sb[1]+sb[2]+sb[3]);
}

// ======== 128 x NT dbuf GEMM: C = A * B^T (+bias) ========
// 256 threads = 4 waves (2x2 of 64x64 for NT=128; 2x2 of 64x32 for NT=64).
// BK=32, double-buffered LDS (32/24 KB) -> 4+ blocks/CU for cross-block
// latency overlap. ONE barrier per K-iter; prefetch of k+1 issued right
// after the barrier, lands during compute of k. BIAS only on blockIdx.z==0
// (z = split-K index). CAUSAL limits k-loop to m0+128.
// global_load_lds dest pattern: LDS element offset 8*t (+const) = lane*16B. legal.
template<bool OUTBF16, bool RELU, bool BIAS, bool CAUSAL, int NT>
__global__ __launch_bounds__(256,4) void gemm_db(
    const unsigned short* __restrict__ Ag, const unsigned short* __restrict__ Bg,
    const float* __restrict__ bias, void* __restrict__ Cg,
    int K, int lda, int ldb, int ldc,
    long long strA, long long strB, long long strC)
{
  constexpr int NJ = NT/32;
  __shared__ unsigned short As[2][128*32];
  __shared__ unsigned short Bs[2][NT*32];
  const unsigned short* Ab = Ag + blockIdx.z*strA;
  const unsigned short* Bb = Bg + blockIdx.z*strB;
  const int m0 = blockIdx.y*128, n0 = blockIdx.x*NT;
  const int t = threadIdx.x;
  const int lane = t & 63, w = t >> 6;
  const int wy = w >> 1, wx = w & 1;
  const int q = lane >> 4, c = lane & 15;
  f32x4 acc[4][NJ] = {};
  const int kend = CAUSAL ? (m0 + 128) : K;
  const int srow = t >> 2;
  const int sk = (t & 3) * 8;                       // LDS chunk (elem off = 8t)
  const int gk = ((t & 3) ^ ((t >> 3) & 3)) * 8;    // swizzled global chunk
  const int rs = (q ^ ((c >> 1) & 3)) * 8;          // swizzled read chunk

#define STAGE(bi, kk) do { \
    async_copy16(Ab + (long long)(m0 + srow)*lda + (kk) + gk,      &As[bi][srow*32 + sk]); \
    async_copy16(Ab + (long long)(m0 + srow + 64)*lda + (kk) + gk, &As[bi][(srow+64)*32 + sk]); \
    async_copy16(Bb + (long long)(n0 + srow)*ldb + (kk) + gk,      &Bs[bi][srow*32 + sk]); \
    if(NT == 128) \
      async_copy16(Bb + (long long)(n0 + srow + 64)*ldb + (kk) + gk, &Bs[bi][(srow+64)*32 + sk]); \
  } while(0)

  STAGE(0, 0);
  int buf = 0;
  for(int k0 = 0; k0 < kend; k0 += 32, buf ^= 1){
    __syncthreads();                          // drains prefetch of `buf`
    if(k0 + 32 < kend) STAGE(buf^1, k0 + 32); // lands during compute below
    bf16x8 af[4], bfr[NJ];
    #pragma unroll
    for(int fi=0; fi<4; fi++) af[fi]  = ld_bf8(&As[buf][(wy*64 + fi*16 + c)*32 + rs]);
    #pragma unroll
    for(int fj=0; fj<NJ; fj++) bfr[fj] = ld_bf8(&Bs[buf][(wx*(NT/2) + fj*16 + c)*32 + rs]);
    #pragma unroll
    for(int fi=0; fi<4; fi++)
      #pragma unroll
      for(int fj=0; fj<NJ; fj++)
        acc[fi][fj] = __builtin_amdgcn_mfma_f32_16x16x32_bf16(af[fi], bfr[fj], acc[fi][fj], 0,0,0);
  }
#undef STAGE
  #pragma unroll
  for(int fi=0; fi<4; fi++){
    #pragma unroll
    for(int fj=0; fj<NJ; fj++){
      const int row = m0 + wy*64 + fi*16 + q*4;
      const int col = n0 + wx*(NT/2) + fj*16 + c;
      const float bv = (BIAS && blockIdx.z==0) ? bias[col] : 0.f;
      #pragma unroll
      for(int r=0; r<4; r++){
        float v = acc[fi][fj][r] + bv;
        if(RELU) v = fmaxf(v, 0.f);
        long long off = blockIdx.z*strC + (long long)(row+r)*ldc + col;
        if(OUTBF16) ((unsigned short*)Cg)[off] = f2bf(v);
        else        ((float*)Cg)[off] = v;
      }
    }
  }
}

// -------- attention pass 1: dsum[b,h,i] += sum_j exp(q_i.k_j / 8) --------
__global__ __launch_bounds__(256) void qk_dsum(
    const unsigned short* __restrict__ qkv, float* __restrict__ dsum)
{
  __shared__ unsigned short As[128*32];
  __shared__ unsigned short Bs[128*32];
  const int bh = blockIdx.z, b = bh >> 3, h = bh & 7;
  const int i0 = blockIdx.y*128, j0 = blockIdx.x*128;
  const unsigned short* Ab = qkv + (long long)b*SEQ*1024 + h*64;
  const unsigned short* Bb = qkv + (long long)b*SEQ*1024 + 512 + h*64;
  const int t = threadIdx.x, lane = t & 63, w = t >> 6;
  const int wy = w >> 1, wx = w & 1, q = lane >> 4, c = lane & 15;
  f32x4 acc[4][4] = {};
  const int srow = t >> 2;
  const int sk = (t & 3) * 8;
  const int gk = ((t & 3) ^ ((t >> 3) & 3)) * 8;
  const int rs = (q ^ ((c >> 1) & 3)) * 8;
  #pragma unroll
  for(int k0 = 0; k0 < 64; k0 += 32){
    async_copy16(Ab + (long long)(i0 + srow)*1024 + k0 + gk,      As + srow*32 + sk);
    async_copy16(Ab + (long long)(i0 + srow + 64)*1024 + k0 + gk, As + (srow+64)*32 + sk);
    async_copy16(Bb + (long long)(j0 + srow)*1024 + k0 + gk,      Bs + srow*32 + sk);
    async_copy16(Bb + (long long)(j0 + srow + 64)*1024 + k0 + gk, Bs + (srow+64)*32 + sk);
    __syncthreads();
    bf16x8 af[4], bfr[4];
    #pragma unroll
    for(int fi=0; fi<4; fi++) af[fi]  = ld_bf8(As + (wy*64 + fi*16 + c)*32 + rs);
    #pragma unroll
    for(int fj=0; fj<4; fj++) bfr[fj] = ld_bf8(Bs + (wx*64 + fj*16 + c)*32 + rs);
    #pragma unroll
    for(int fi=0; fi<4; fi++)
      #pragma unroll
      for(int fj=0; fj<4; fj++)
        acc[fi][fj] = __builtin_amdgcn_mfma_f32_16x16x32_bf16(af[fi], bfr[fj], acc[fi][fj], 0,0,0);
    __syncthreads();
  }
  #pragma unroll
  for(int fi=0; fi<4; fi++){
    #pragma unroll
    for(int r=0; r<4; r++){
      float s = 0.f;
      #pragma unroll
      for(int fj=0; fj<4; fj++) s += __expf(acc[fi][fj][r]*0.125f);
      s += __shfl_xor(s,1,64); s += __shfl_xor(s,2,64);
      s += __shfl_xor(s,4,64); s += __shfl_xor(s,8,64);
      if(c == 0)
        atomicAdd(&dsum[(long long)bh*SEQ + i0 + wy*64 + fi*16 + q*4 + r], s);
    }
  }
}

// -------- attention pass 2: averaged A + pos/causal + 2nd softmax numerator --------
__global__ __launch_bounds__(256) void attn_w(
    const unsigned short* __restrict__ qkv, const float* __restrict__ dsum,
    unsigned short* __restrict__ Wm, float* __restrict__ Dsum2)
{
  __shared__ unsigned short As[64*32];
  __shared__ unsigned short Bs[64*32];
  __shared__ float inv8[8][64];
  const int b = blockIdx.y;
  int x = blockIdx.x;
  int it = 0;
  while((it+1)*(it+2)/2 <= x) ++it;
  const int jt = x - it*(it+1)/2;
  const int i0 = it*64, j0 = jt*64;
  const int t = threadIdx.x, lane = t & 63, w = t >> 6;
  const int q = lane >> 4, c = lane & 15;
  for(int u = t; u < 512; u += 256){
    int h = u >> 6, r = u & 63;
    inv8[h][r] = 1.f/(8.f*dsum[((long long)(b*8 + h))*SEQ + i0 + r]);
  }
  const unsigned short* Qb = qkv + (long long)b*SEQ*1024;
  const int srow = t >> 2;
  const int sk = (t & 3) * 8;
  const int gk = ((t & 3) ^ ((t >> 3) & 3)) * 8;
  const int rs = (q ^ ((c >> 1) & 3)) * 8;
  f32x4 at[4] = {};
  for(int h = 0; h < 8; h++){
    f32x4 l[4] = {};
    #pragma unroll
    for(int k0 = 0; k0 < 64; k0 += 32){
      __syncthreads();
      async_copy16(Qb + (long long)(i0 + srow)*1024 + h*64 + k0 + gk,       As + srow*32 + sk);
      async_copy16(Qb + (long long)(j0 + srow)*1024 + 512 + h*64 + k0 + gk, Bs + srow*32 + sk);
      __syncthreads();
      bf16x8 af = ld_bf8(As + (w*16 + c)*32 + rs);
      bf16x8 bfr[4];
      #pragma unroll
      for(int fj=0; fj<4; fj++) bfr[fj] = ld_bf8(Bs + (fj*16 + c)*32 + rs);
      #pragma unroll
      for(int fj=0; fj<4; fj++)
        l[fj] = __builtin_amdgcn_mfma_f32_16x16x32_bf16(af, bfr[fj], l[fj], 0,0,0);
    }
    #pragma unroll
    for(int r=0; r<4; r++){
      float iv = inv8[h][w*16 + q*4 + r];
      #pragma unroll
      for(int fj=0; fj<4; fj++)
        at[fj][r] += __expf(l[fj][r]*0.125f)*iv;
    }
  }
  float Dacc[4] = {};
  #pragma unroll
  for(int fj=0; fj<4; fj++){
    #pragma unroll
    for(int r=0; r<4; r++){
      const int i = i0 + w*16 + q*4 + r;
      const int j = j0 + fj*16 + c;
      float wv = 0.f;
      if(j <= i) wv = __expf(at[fj][r] + __expf((float)(j - i)*0.1f));
      Wm[((long long)(b*SEQ + i))*SEQ + j] = f2bf(wv);
      Dacc[r] += wv;
    }
  }
  #pragma unroll
  for(int r=0; r<4; r++){
    Dacc[r] += __shfl_xor(Dacc[r],1,64); Dacc[r] += __shfl_xor(Dacc[r],2,64);
    Dacc[r] += __shfl_xor(Dacc[r],4,64); Dacc[r] += __shfl_xor(Dacc[r],8,64);
    if(c == 0)
      atomicAdd(&Dsum2[(long long)b*SEQ + i0 + w*16 + q*4 + r], Dacc[r]);
  }
}

// ------- LDS-tiled transpose: Xb [8192,512] -> XT [512,8192] -------
__global__ __launch_bounds__(256) void transpose_bf16(
    const unsigned short* __restrict__ src, unsigned short* __restrict__ dst)
{
  __shared__ unsigned short tile[64*65];
  const int bx = blockIdx.x;
  const int by = blockIdx.y;
  const int t = threadIdx.x;
  #pragma unroll
  for(int p=0; p<2; p++){
    int idx = t + p*256;
    int r = idx >> 3, cc = (idx & 7)*8;
    alignas(16) unsigned short e[8];
    *(uint4*)e = *(const uint4*)(src + (long long)(by*64 + r)*512 + bx*64 + cc);
    #pragma unroll
    for(int u=0; u<8; u++) tile[r*65 + cc + u] = e[u];
  }
  __syncthreads();
  #pragma unroll
  for(int p=0; p<2; p++){
    int idx = t + p*256;
    int r2 = idx >> 3, c2 = (idx & 7)*8;
    alignas(16) unsigned short e[8];
    #pragma unroll
    for(int u=0; u<8; u++) e[u] = tile[(c2+u)*65 + r2];
    *(uint4*)(dst + (long long)(bx*64 + r2)*8192 + by*64 + c2) = *(const uint4*)e;
  }
}

// ------- fused residual(+1/Dsum2 scale) + LN1 + LN2; writes fp32 + bf16 -------
__global__ __launch_bounds__(256) void residual_ln2(
    const float* __restrict__ X, const float* __restrict__ SA,
    const float* __restrict__ Dsum2,
    const float* __restrict__ g1, const float* __restrict__ b1,
    const float* __restrict__ g2, const float* __restrict__ b2,
    float* __restrict__ XO, unsigned short* __restrict__ Xb)
{
  const long long row = blockIdx.x;
  const int t = threadIdx.x;
  const float s = 1.f/Dsum2[row];
  float v0 = X[row*EMB + t]       + SA[row*EMB + t]*s;
  float v1 = X[row*EMB + t + 256] + SA[row*EMB + t + 256]*s;
  float2 ss = block_sum2(v0+v1, v0*v0+v1*v1);
  float mean = ss.x*(1.f/EMB);
  float var  = ss.y*(1.f/EMB) - mean*mean;
  float rstd = rsqrtf(var + LNEPS);
  float y0 = (v0-mean)*rstd*g1[t]     + b1[t];
  float y1 = (v1-mean)*rstd*g1[t+256] + b1[t+256];
  ss = block_sum2(y0+y1, y0*y0+y1*y1);
  mean = ss.x*(1.f/EMB);
  var  = ss.y*(1.f/EMB) - mean*mean;
  rstd = rsqrtf(var + LNEPS);
  float o0 = (y0-mean)*rstd*g2[t]     + b2[t];
  float o1 = (y1-mean)*rstd*g2[t+256] + b2[t+256];
  XO[row*EMB + t] = o0;       XO[row*EMB + t + 256] = o1;
  Xb[row*EMB + t] = f2bf(o0); Xb[row*EMB + t + 256] = f2bf(o1);
}

// ------- residual(2 partials) + LN; writes fp32 + bf16 -------
__global__ __launch_bounds__(256) void residual_ln(
    const float* __restrict__ X, const float* __restrict__ R1,
    const float* __restrict__ R2,
    const float* __restrict__ g, const float* __restrict__ b,
    float* __restrict__ XO, unsigned short* __restrict__ Xb)
{
  const long long row = blockIdx.x;
  const int t = threadIdx.x;
  float v0 = X[row*EMB + t]       + R1[row*EMB + t]       + R2[row*EMB + t];
  float v1 = X[row*EMB + t + 256] + R1[row*EMB + t + 256] + R2[row*EMB + t + 256];
  float2 ss = block_sum2(v0+v1, v0*v0+v1*v1);
  float mean = ss.x*(1.f/EMB);
  float var  = ss.y*(1.f/EMB) - mean*mean;
  float rstd = rsqrtf(var + LNEPS);
  float o0 = (v0-mean)*rstd*g[t]     + b[t];
  float o1 = (v1-mean)*rstd*g[t+256] + b[t+256];
  XO[row*EMB + t] = o0;       XO[row*EMB + t + 256] = o1;
  Xb[row*EMB + t] = f2bf(o0); Xb[row*EMB + t + 256] = f2bf(o1);
}

// ------- initial x -> X fp32 copy + bf16 -------
__global__ __launch_bounds__(256) void init_x(
    const float* __restrict__ in, float* __restrict__ XO,
    unsigned short* __restrict__ Xb)
{
  const long long row = blockIdx.x;
  const int t = threadIdx.x;
  float v0 = in[row*EMB + t];
  float v1 = in[row*EMB + t + 256];
  XO[row*EMB + t] = v0;       XO[row*EMB + t + 256] = v1;
  Xb[row*EMB + t] = f2bf(v0); Xb[row*EMB + t + 256] = f2bf(v1);
}

// ------- fp32 -> bf16 convert (n multiple of 4) -------
__global__ __launch_bounds__(256) void cvt_bf16(
    const float* __restrict__ src, unsigned short* __restrict__ dst, long long n)
{
  long long i = ((long long)blockIdx.x*256 + threadIdx.x)*4;
  if(i < n){
    float4 v = *(const float4*)(src + i);
    ushort4 o = make_ushort4(f2bf(v.x), f2bf(v.y), f2bf(v.z), f2bf(v.w));
    *(ushort4*)(dst + i) = o;
  }
}

// ------- Wqkv fp32 -> bf16, q/k rows only (first 1024 of each 1536) -------
__global__ __launch_bounds__(256) void cvt_qkv(
    const float* __restrict__ src, unsigned short* __restrict__ dst)
{
  long long i = ((long long)blockIdx.x*256 + threadIdx.x)*4;   // over 4*1024*512
  int layer = (int)(i >> 19);
  long long within = i & ((1LL<<19)-1);
  float4 v = *(const float4*)(src + (long long)layer*1536*512 + within);
  ushort4 o = make_ushort4(f2bf(v.x), f2bf(v.y), f2bf(v.z), f2bf(v.w));
  *(ushort4*)(dst + i) = o;
}

extern "C" void kernel_launch(void* const* d_in, const int* in_sizes, int n_in,
                              void* d_out, int out_size, void* d_ws, size_t ws_size,
                              hipStream_t stream)
{
  const float* x_in = (const float*)d_in[0];
  const float* Wqkv = (const float*)d_in[1];
  const float* bqkv = (const float*)d_in[2];
  const float* W1   = (const float*)d_in[3];
  const float* b1   = (const float*)d_in[4];
  const float* W2   = (const float*)d_in[5];
  const float* b2   = (const float*)d_in[6];
  const float* g1   = (const float*)d_in[7];
  const float* bt1  = (const float*)d_in[8];
  const float* g2   = (const float*)d_in[9];
  const float* bt2  = (const float*)d_in[10];
  const float* g3   = (const float*)d_in[11];
  const float* bt3  = (const float*)d_in[12];

  float* X = (float*)d_out;                               // [8192,512] fp32

  char* ws = (char*)d_ws;
  unsigned short* qkv    = (unsigned short*)(ws);                       // 16MB [8192,1024] bf16 (q,k)
  unsigned short* hbuf   = (unsigned short*)(ws + ((size_t)16<<20));    // 32MB [8192,2048] bf16
  unsigned short* Wm     = (unsigned short*)(ws + ((size_t)48<<20));    // 16MB [8,1024,1024] bf16
  float*          tmp    = (float*)         (ws + ((size_t)64<<20));    // 16MB [8192,512] fp32 (sa / ffn2 p0)
  float*          tmp2   = (float*)         (ws + ((size_t)80<<20));    // 16MB ffn2 p1
  unsigned short* Xb     = (unsigned short*)(ws + ((size_t)96<<20));    // 8MB  [8192,512] bf16
  unsigned short* XT     = (unsigned short*)(ws + ((size_t)104<<20));   // 8MB  [512,8192] bf16
  unsigned short* Wqkvb  = (unsigned short*)(ws + ((size_t)112<<20));   // 4MB  [4,1024,512]
  unsigned short* W1b    = (unsigned short*)(ws + ((size_t)118<<20));   // 8MB
  unsigned short* W2b    = (unsigned short*)(ws + ((size_t)126<<20));   // 8MB
  float*          dsum   = (float*)         (ws + ((size_t)134<<20));   // 256KB [8,8,1024]
  float*          Dsum2  = (float*)         (ws + ((size_t)134<<20) + (256<<10)); // 32KB [8192]

  // weight conversions (same work every call)
  cvt_qkv<<<2048, 256, 0, stream>>>(Wqkv, Wqkvb);
  cvt_bf16<<<4096, 256, 0, stream>>>(W1, W1b, (long long)4*FFD*EMB);
  cvt_bf16<<<4096, 256, 0, stream>>>(W2, W2b, (long long)4*EMB*FFD);
  init_x<<<NROWS, 256, 0, stream>>>(x_in, X, Xb);
  transpose_bf16<<<dim3(8,128), 256, 0, stream>>>(Xb, XT);

  for(int d=0; d<4; d++){
    hipMemsetAsync(dsum, 0, (256<<10) + (32<<10), stream);

    // qk = X * Wqkv[0:1024]^T + bqkv   (128x128 dbuf, 512 blocks)
    gemm_db<true,false,true,false,128><<<dim3(8, 64, 1), 256, 0, stream>>>(
        Xb, Wqkvb + (size_t)d*1024*EMB, bqkv + (size_t)d*1536, qkv,
        EMB, EMB, EMB, 1024, 0, 0, 0);

    // per-head full-row softmax denominators
    qk_dsum<<<dim3(8, 8, 64), 256, 0, stream>>>(qkv, dsum);

    // averaged A + causal/pos re-softmax numerator -> Wm, Dsum2
    attn_w<<<dim3(136, NB), 256, 0, stream>>>(qkv, dsum, Wm, Dsum2);

    // sa = W @ x  (B = XT per batch, causal K limit), 128x64 dbuf, 512 blocks
    gemm_db<false,false,false,true,64><<<dim3(8, 8, NB), 256, 0, stream>>>(
        Wm, XT, nullptr, tmp,
        SEQ, SEQ, NROWS, EMB,
        (long long)SEQ*SEQ, 1024, (long long)SEQ*EMB);

    // x = LN2(LN1(x + sa/Dsum2))
    residual_ln2<<<NROWS, 256, 0, stream>>>(X, tmp, Dsum2,
        g1 + d*EMB, bt1 + d*EMB, g2 + d*EMB, bt2 + d*EMB, X, Xb);

    // h = relu(x*W1^T + b1)   (128x128 dbuf, 1024 blocks)
    gemm_db<true,true,true,false,128><<<dim3(16, 64, 1), 256, 0, stream>>>(
        Xb, W1b + (size_t)d*FFD*EMB, b1 + (size_t)d*FFD, hbuf,
        EMB, EMB, EMB, FFD, 0, 0, 0);

    // ff = h*W2^T + b2, split-K=2 (partials tmp, tmp2; bias on z==0), 512 blocks
    gemm_db<false,false,true,false,128><<<dim3(4, 64, 2), 256, 0, stream>>>(
        hbuf, W2b + (size_t)d*EMB*FFD, b2 + (size_t)d*EMB, tmp,
        1024, FFD, FFD, EMB,
        1024, 1024, (long long)NROWS*EMB);

    // x = LN3(x + ff0 + ff1)
    residual_ln<<<NROWS, 256, 0, stream>>>(X, tmp, tmp2,
        g3 + d*EMB, bt3 + d*EMB, X, Xb);
    transpose_bf16<<<dim3(8,128), 256, 0, stream>>>(Xb, XT);
  }
}